// Round 5
// baseline (533.807 us; speedup 1.0000x reference)
//
#include <hip/hip_runtime.h>
#include <hip/hip_bf16.h>
#include <math.h>

// ---------------------------------------------------------------------------
// TransformerBlock on MI355X (gfx950).
// GEMMs: 256x256 8-phase schedule (T2 swizzle + T3/T4 counted vmcnt + T5
// setprio), bf16 operands (A[M,K], B^T[N,K]), fp32 acc.
// Attn: round-4 LDS-staged double-buffered flash attention (unchanged).
// ---------------------------------------------------------------------------

typedef __attribute__((ext_vector_type(8))) short bf16x8;
typedef __attribute__((ext_vector_type(4))) float f32x4;

#define AS1 __attribute__((address_space(1)))
#define AS3 __attribute__((address_space(3)))

__device__ __forceinline__ void gl_lds16(const void* g, void* l) {
  __builtin_amdgcn_global_load_lds((const AS1 void*)g, (AS3 void*)l, 16, 0, 0);
}

__device__ __forceinline__ float gelu_f(float x) {
  const float c = 0.7978845608028654f;  // sqrt(2/pi)
  return 0.5f * x * (1.0f + tanhf(c * (x + 0.044715f * x * x * x)));
}

// ---------------------------------------------------------------------------
// Weight transpose + fp32->bf16 convert:  W [K,N] fp32  ->  WT [N,K] bf16
// ---------------------------------------------------------------------------
__global__ void __launch_bounds__(256) tcvt_kernel(
    const float* __restrict__ W, __hip_bfloat16* __restrict__ WT, int K, int N) {
  __shared__ float t[32][33];
  const int n0 = blockIdx.x * 32, k0 = blockIdx.y * 32;
  const int tx = threadIdx.x, ty0 = threadIdx.y;  // 32 x 8
#pragma unroll
  for (int i = 0; i < 4; i++) {
    int ty = ty0 + i * 8;
    t[ty][tx] = W[(size_t)(k0 + ty) * N + n0 + tx];
  }
  __syncthreads();
#pragma unroll
  for (int i = 0; i < 4; i++) {
    int ty = ty0 + i * 8;
    WT[(size_t)(n0 + ty) * K + k0 + tx] = __float2bfloat16(t[tx][ty]);
  }
}

// ---------------------------------------------------------------------------
// V transpose: qkv[b*2048+s][3072] (V at col 2048+h*64+hd) -> vt[(bh*64+hd)][s]
// ---------------------------------------------------------------------------
__global__ void __launch_bounds__(256) vtr_kernel(
    const __hip_bfloat16* __restrict__ qkv, __hip_bfloat16* __restrict__ vt) {
  __shared__ __hip_bfloat16 t[32][33];
  const int s0 = blockIdx.x * 32;
  const int hd0 = blockIdx.y * 32;
  const int bh = blockIdx.z;
  const int b = bh >> 4, h = bh & 15;
  const int tx = threadIdx.x, ty0 = threadIdx.y;  // 32 x 8
  const __hip_bfloat16* src =
      qkv + (size_t)(b * 2048 + s0) * 3072 + 2048 + h * 64 + hd0;
#pragma unroll
  for (int i = 0; i < 4; i++) {
    int ty = ty0 + i * 8;
    t[ty][tx] = src[(size_t)ty * 3072 + tx];  // t[s_local][hd_local]
  }
  __syncthreads();
  __hip_bfloat16* dst = vt + ((size_t)bh * 64 + hd0) * 2048 + s0;
#pragma unroll
  for (int i = 0; i < 4; i++) {
    int ty = ty0 + i * 8;
    dst[(size_t)ty * 2048 + tx] = t[tx][ty];
  }
}

// ---------------------------------------------------------------------------
// LayerNorm over D=1024, one block (256 thr) per row, fp32 in -> bf16 out
// ---------------------------------------------------------------------------
__global__ void __launch_bounds__(256) ln_kernel(
    const float* __restrict__ x, const float* __restrict__ gma,
    const float* __restrict__ bta, __hip_bfloat16* __restrict__ out) {
  const int row = blockIdx.x;
  const int tid = threadIdx.x;
  const float4 v = ((const float4*)(x + (size_t)row * 1024))[tid];
  float s = v.x + v.y + v.z + v.w;
  float s2 = v.x * v.x + v.y * v.y + v.z * v.z + v.w * v.w;
#pragma unroll
  for (int m = 32; m; m >>= 1) {
    s += __shfl_xor(s, m);
    s2 += __shfl_xor(s2, m);
  }
  __shared__ float red[8];
  const int w = tid >> 6, lane = tid & 63;
  if (lane == 0) { red[w] = s; red[4 + w] = s2; }
  __syncthreads();
  s = red[0] + red[1] + red[2] + red[3];
  s2 = red[4] + red[5] + red[6] + red[7];
  const float mu = s * (1.0f / 1024.0f);
  const float var = s2 * (1.0f / 1024.0f) - mu * mu;
  const float rs = rsqrtf(var + 1e-5f);
  const float4 gv = ((const float4*)gma)[tid];
  const float4 bv = ((const float4*)bta)[tid];
  __hip_bfloat16* orow = out + (size_t)row * 1024 + tid * 4;
  orow[0] = __float2bfloat16((v.x - mu) * rs * gv.x + bv.x);
  orow[1] = __float2bfloat16((v.y - mu) * rs * gv.y + bv.y);
  orow[2] = __float2bfloat16((v.z - mu) * rs * gv.z + bv.z);
  orow[3] = __float2bfloat16((v.w - mu) * rs * gv.w + bv.w);
}

// ---------------------------------------------------------------------------
// GEMM 256x256, 8-phase: C = A[M,K] * B^T[N,K], bf16 in, fp32 acc.
// 512 thr (8 waves: 2M x 4N), per-wave C = 128x64. BK=64, K-tile = 4 phases
// of (ks,mh): (0,0),(0,1),(1,0),(1,1); 16 MFMA + 8 ds_read_b128 per phase.
// LDS [2buf][A:2ks x 256 x 32 | B: same] = 128KB, slot^=(row&3) swizzle on
// both gl_lds source and ds_read (conflict-free b128, proven in attn R4).
// Stage units: A-quarters (mh,ks) 8KB, B-halves (hf,ks) 8KB; 1 gl_lds per
// thread per unit; staged into regions freed by the previous phase.
// Counted vmcnt (12,13,12,13) -- never drains in the main loop (T4).
// Ledger (per-wave calls): prologue 13 = t0 all 8 + t1 first 5; per tile:
// ph0 stages t+1 [Am1k1,Bk1h0,Bk1h1], ph1: t+2 Am0k0, ph2: t+2 [Am1k0,
// Bk0h0,Bk0h1], ph3: t+2 Am0k1. Tail clamps re-stage own tile (idempotent).
// EPI 0: bf16 | 1: fp32 +bias+resid | 2: bf16 gelu(.+bias)
// ---------------------------------------------------------------------------
template <int EPI>
__global__ void __launch_bounds__(512, 2) gemm256(
    const __hip_bfloat16* __restrict__ Ap, const __hip_bfloat16* __restrict__ Bp,
    void* __restrict__ outp, const float* __restrict__ bias,
    const float* __restrict__ resid, int N, int K) {
  __shared__ __attribute__((aligned(128))) char smem[131072];
  const int tid = threadIdx.x;
  const int lane = tid & 63, w = tid >> 6;
  const int wr = w >> 2, wc = w & 3;          // 2M x 4N waves
  const int cr = lane & 15, g = lane >> 4;
  const int rsel = lane >> 2;                  // staging: row within 16-row strip
  const int slot8 = ((lane & 3) ^ (rsel & 3)) * 8;  // pre-swizzled src slot
  const int sg8 = (g ^ (cr & 3)) * 8;          // swizzled read slot

  // XCD swizzle (grids all %8==0)
  const int nwg = gridDim.x * gridDim.y;
  const int orig = blockIdx.y * gridDim.x + blockIdx.x;
  const int swz = (orig & 7) * (nwg >> 3) + (orig >> 3);
  const int bm = swz % gridDim.x, bn = swz / gridDim.x;
  const int bmr = bm * 256, bnr = bn * 256;
  const int nkt = K >> 6;

  // Stage macros: 1 gl_lds per thread per unit.
#define STG_A(tt, mh, ks)                                                       \
  gl_lds16(Ap + (size_t)(bmr + wr * 128 + (mh) * 64 + (wc & 3) * 16 + rsel) * K \
               + (tt) * 64 + (ks) * 32 + slot8,                                 \
           smem + ((tt) & 1) * 65536 + (ks) * 16384 +                           \
               (wr * 128 + (mh) * 64 + (wc & 3) * 16) * 64)
#define STG_B(tt, hf, ks)                                                       \
  gl_lds16(Bp + (size_t)(bnr + (hf) * 128 + w * 16 + rsel) * K                  \
               + (tt) * 64 + (ks) * 32 + slot8,                                 \
           smem + ((tt) & 1) * 65536 + 32768 + (ks) * 16384 +                   \
               ((hf) * 128 + w * 16) * 64)
#define VM(n) asm volatile("s_waitcnt vmcnt(" #n ")" ::: "memory")

  f32x4 acc[8][4];
#pragma unroll
  for (int i = 0; i < 8; i++)
#pragma unroll
    for (int j = 0; j < 4; j++) acc[i][j] = (f32x4){0.f, 0.f, 0.f, 0.f};

#define COMPUTE(bb, ks, mh)                                                     \
  {                                                                             \
    const __hip_bfloat16* pA =                                                  \
        (const __hip_bfloat16*)(smem + (bb) * 65536 + (ks) * 16384);            \
    const __hip_bfloat16* pB =                                                  \
        (const __hip_bfloat16*)(smem + (bb) * 65536 + 32768 + (ks) * 16384);    \
    bf16x8 av[4], bv[4];                                                        \
    _Pragma("unroll") for (int m = 0; m < 4; m++)                               \
        av[m] = *(const bf16x8*)(pA + (wr * 128 + (mh) * 64 + m * 16 + cr) * 32 \
                                 + sg8);                                        \
    _Pragma("unroll") for (int n = 0; n < 4; n++)                               \
        bv[n] = *(const bf16x8*)(pB + (wc * 64 + n * 16 + cr) * 32 + sg8);      \
    __builtin_amdgcn_s_setprio(1);                                              \
    _Pragma("unroll") for (int m = 0; m < 4; m++)                               \
        _Pragma("unroll") for (int n = 0; n < 4; n++)                           \
            acc[(mh) * 4 + m][n] = __builtin_amdgcn_mfma_f32_16x16x32_bf16(     \
                av[m], bv[n], acc[(mh) * 4 + m][n], 0, 0, 0);                   \
    __builtin_amdgcn_s_setprio(0);                                              \
  }

#define TILE_BODY(bb, t)                                                        \
  {                                                                             \
    const int tsA = ((t) + 1 < nkt) ? (t) + 1 : (t) - 1;                        \
    STG_A(tsA, 1, 1); STG_B(tsA, 0, 1); STG_B(tsA, 1, 1);                       \
    VM(12); __builtin_amdgcn_s_barrier();                                       \
    COMPUTE(bb, 0, 0);                                                          \
    __builtin_amdgcn_s_barrier();                                               \
    const int tsB = ((t) + 2 < nkt) ? (t) + 2 : (t);                            \
    STG_A(tsB, 0, 0);                                                           \
    VM(13); __builtin_amdgcn_s_barrier();                                       \
    COMPUTE(bb, 0, 1);                                                          \
    __builtin_amdgcn_s_barrier();                                               \
    STG_A(tsB, 1, 0); STG_B(tsB, 0, 0); STG_B(tsB, 1, 0);                       \
    VM(12); __builtin_amdgcn_s_barrier();                                       \
    COMPUTE(bb, 1, 0);                                                          \
    __builtin_amdgcn_s_barrier();                                               \
    STG_A(tsB, 0, 1);                                                           \
    VM(13); __builtin_amdgcn_s_barrier();                                       \
    COMPUTE(bb, 1, 1);                                                          \
    __builtin_amdgcn_s_barrier();                                               \
  }

  // Prologue: tile0 all 8 units, tile1 first 5 (ledger calls #1..#13).
  STG_A(0, 0, 0); STG_A(0, 1, 0); STG_B(0, 0, 0); STG_B(0, 1, 0);
  STG_A(0, 0, 1); STG_A(0, 1, 1); STG_B(0, 0, 1); STG_B(0, 1, 1);
  STG_A(1, 0, 0); STG_A(1, 1, 0); STG_B(1, 0, 0); STG_B(1, 1, 0);
  STG_A(1, 0, 1);

  for (int t = 0; t < nkt; t += 2) {
    TILE_BODY(0, t);
    TILE_BODY(1, t + 1);
  }

  // Epilogue. C/D layout: col = lane&15, row = (lane>>4)*4 + reg.
#pragma unroll
  for (int m = 0; m < 8; m++) {
#pragma unroll
    for (int rr = 0; rr < 4; rr++) {
      const int row = bmr + wr * 128 + m * 16 + g * 4 + rr;
#pragma unroll
      for (int n = 0; n < 4; n++) {
        const int col = bnr + wc * 64 + n * 16 + cr;
        float v = acc[m][n][rr];
        if (EPI == 0) {
          ((__hip_bfloat16*)outp)[(size_t)row * N + col] = __float2bfloat16(v);
        } else if (EPI == 1) {
          v += bias[col] + resid[(size_t)row * N + col];
          ((float*)outp)[(size_t)row * N + col] = v;
        } else {
          v = gelu_f(v + bias[col]);
          ((__hip_bfloat16*)outp)[(size_t)row * N + col] = __float2bfloat16(v);
        }
      }
    }
  }
#undef STG_A
#undef STG_B
#undef VM
#undef COMPUTE
#undef TILE_BODY
}

// ---------------------------------------------------------------------------
// Flash attention, causal (round-4 version, unchanged). qkv [8192,3072] bf16,
// vt [bh][hd=64][s] bf16. 256 thr (4 waves), QBLK=128, KVBLK=64, dbuf LDS,
// XOR-swizzled staging, exp2-domain online softmax.
// ---------------------------------------------------------------------------
__global__ void __launch_bounds__(256) attn_kernel(
    const __hip_bfloat16* __restrict__ qkv, const __hip_bfloat16* __restrict__ vt,
    __hip_bfloat16* __restrict__ o) {
  __shared__ __hip_bfloat16 sK[2][64 * 64];   // [kv][hd], slot-swizzled
  __shared__ __hip_bfloat16 sV[2][64 * 64];   // [hd][kv], slot-swizzled
  __shared__ __hip_bfloat16 pl[4][16][64];    // per-wave P bounce, swizzled
  const int tid = threadIdx.x, lane = tid & 63, w = tid >> 6;
  const int bid = blockIdx.x;                  // 0..1023
  const int bh = (bid & 7) + 8 * ((bid >> 3) & 7);
  const int qt = 15 - (bid >> 6);              // heavy q-tiles first
  const int b = bh >> 4, h = bh & 15;
  const int cr = lane & 15, g = lane >> 4;
  const int qr0 = qt * 128 + w * 32;           // wave's first q row
  const float NEG = -1e30f;
  const float SC2 = 0.18033688011112042f;      // 0.125 * log2(e)
  const int sw = cr & 7;                       // read-side swizzle key
  const int sg0 = (g ^ sw) * 8;                // swizzled 16B slot (elems)
  const int sg1 = ((g ^ sw) ^ 4) * 8;

  bf16x8 aq[2][2];
#pragma unroll
  for (int m = 0; m < 2; m++) {
    const __hip_bfloat16* qp =
        qkv + (size_t)(b * 2048 + qr0 + m * 16 + cr) * 3072 + h * 64 + g * 8;
    aq[m][0] = *(const bf16x8*)qp;
    aq[m][1] = *(const bf16x8*)(qp + 32);
  }
  const __hip_bfloat16* kbase = qkv + (size_t)(b * 2048) * 3072 + 1024 + h * 64;
  const __hip_bfloat16* vbase = vt + (size_t)bh * 64 * 2048;

  const int l8 = lane >> 3, c8 = lane & 7;
  const int c8s = (c8 ^ l8) * 8;  // pre-swizzled global source slot (elems)
#define STAGE_TILE(bi, ktile)                                                   \
  {                                                                             \
    _Pragma("unroll") for (int i = 0; i < 2; i++) {                             \
      const int rb = (i * 4 + w) * 8 + l8;                                      \
      gl_lds16(kbase + (size_t)((ktile) * 64 + rb) * 3072 + c8s,                \
               &sK[bi][(i * 4 + w) * 512]);                                     \
      gl_lds16(vbase + (size_t)rb * 2048 + (ktile) * 64 + c8s,                  \
               &sV[bi][(i * 4 + w) * 512]);                                     \
    }                                                                           \
  }

  f32x4 oacc[2][4];
#pragma unroll
  for (int m = 0; m < 2; m++)
#pragma unroll
    for (int i = 0; i < 4; i++) oacc[m][i] = (f32x4){0.f, 0.f, 0.f, 0.f};
  float mrow[2][4], lrow[2][4];
#pragma unroll
  for (int m = 0; m < 2; m++)
#pragma unroll
    for (int rr = 0; rr < 4; rr++) { mrow[m][rr] = NEG; lrow[m][rr] = 0.f; }

  const int nkt = (qt + 1) * 2;
  STAGE_TILE(0, 0);
  asm volatile("s_waitcnt vmcnt(0)" ::: "memory");
  __syncthreads();
  int cur = 0;

  for (int kt = 0; kt < nkt; ++kt) {
    if (kt + 1 < nkt) STAGE_TILE(cur ^ 1, kt + 1);

    if (kt * 64 <= qr0 + 31) {
      f32x4 s[2][4];
      __builtin_amdgcn_s_setprio(1);
#pragma unroll
      for (int nf = 0; nf < 4; nf++) {
        const bf16x8 bk0 = *(const bf16x8*)&sK[cur][(nf * 16 + cr) * 64 + sg0];
        const bf16x8 bk1 = *(const bf16x8*)&sK[cur][(nf * 16 + cr) * 64 + sg1];
#pragma unroll
        for (int m = 0; m < 2; m++) {
          f32x4 z = (f32x4){0.f, 0.f, 0.f, 0.f};
          z = __builtin_amdgcn_mfma_f32_16x16x32_bf16(aq[m][0], bk0, z, 0, 0, 0);
          z = __builtin_amdgcn_mfma_f32_16x16x32_bf16(aq[m][1], bk1, z, 0, 0, 0);
          s[m][nf] = z * SC2;
        }
      }
      __builtin_amdgcn_s_setprio(0);
      if (kt * 64 + 63 > qr0) {
#pragma unroll
        for (int m = 0; m < 2; m++)
#pragma unroll
          for (int nf = 0; nf < 4; nf++)
#pragma unroll
            for (int rr = 0; rr < 4; rr++) {
              const int kvcol = kt * 64 + nf * 16 + cr;
              const int qrow = qr0 + m * 16 + g * 4 + rr;
              if (kvcol > qrow) s[m][nf][rr] = NEG;
            }
      }
#pragma unroll
      for (int m = 0; m < 2; m++) {
        float scl[4];
#pragma unroll
        for (int rr = 0; rr < 4; rr++) {
          float v = fmaxf(fmaxf(s[m][0][rr], s[m][1][rr]),
                          fmaxf(s[m][2][rr], s[m][3][rr]));
          v = fmaxf(v, __shfl_xor(v, 1));
          v = fmaxf(v, __shfl_xor(v, 2));
          v = fmaxf(v, __shfl_xor(v, 4));
          v = fmaxf(v, __shfl_xor(v, 8));
          const float mn = fmaxf(mrow[m][rr], v);
          scl[rr] = exp2f(mrow[m][rr] - mn);
          mrow[m][rr] = mn;
        }
        float rsum[4] = {0.f, 0.f, 0.f, 0.f};
#pragma unroll
        for (int nf = 0; nf < 4; nf++)
#pragma unroll
          for (int rr = 0; rr < 4; rr++) {
            const float p = exp2f(s[m][nf][rr] - mrow[m][rr]);
            s[m][nf][rr] = p;
            rsum[rr] += p;
          }
#pragma unroll
        for (int rr = 0; rr < 4; rr++) {
          float v = rsum[rr];
          v += __shfl_xor(v, 1);
          v += __shfl_xor(v, 2);
          v += __shfl_xor(v, 4);
          v += __shfl_xor(v, 8);
          lrow[m][rr] = lrow[m][rr] * scl[rr] + v;
        }
#pragma unroll
        for (int nf = 0; nf < 4; nf++) {
          f32x4 t = oacc[m][nf];
          t[0] *= scl[0]; t[1] *= scl[1]; t[2] *= scl[2]; t[3] *= scl[3];
          oacc[m][nf] = t;
        }
#pragma unroll
        for (int nf = 0; nf < 4; nf++)
#pragma unroll
          for (int rr = 0; rr < 4; rr++) {
            const int prow = g * 4 + rr;
            pl[w][prow][(nf * 16 + cr) ^ ((prow & 7) << 3)] =
                __float2bfloat16(s[m][nf][rr]);
          }
        const bf16x8 pa0 = *(const bf16x8*)&pl[w][cr][sg0];
        const bf16x8 pa1 = *(const bf16x8*)&pl[w][cr][sg1];
        __builtin_amdgcn_s_setprio(1);
#pragma unroll
        for (int nf = 0; nf < 4; nf++) {
          const bf16x8 bv0 = *(const bf16x8*)&sV[cur][(nf * 16 + cr) * 64 + sg0];
          const bf16x8 bv1 = *(const bf16x8*)&sV[cur][(nf * 16 + cr) * 64 + sg1];
          oacc[m][nf] = __builtin_amdgcn_mfma_f32_16x16x32_bf16(pa0, bv0, oacc[m][nf], 0, 0, 0);
          oacc[m][nf] = __builtin_amdgcn_mfma_f32_16x16x32_bf16(pa1, bv1, oacc[m][nf], 0, 0, 0);
        }
        __builtin_amdgcn_s_setprio(0);
      }
    }

    if (kt + 1 < nkt) {
      asm volatile("s_waitcnt vmcnt(0)" ::: "memory");
      __syncthreads();
      cur ^= 1;
    }
  }

#pragma unroll
  for (int m = 0; m < 2; m++)
#pragma unroll
    for (int nf = 0; nf < 4; nf++)
#pragma unroll
      for (int rr = 0; rr < 4; rr++) {
        const int row = qr0 + m * 16 + g * 4 + rr;
        o[(size_t)(b * 2048 + row) * 1024 + h * 64 + nf * 16 + cr] =
            __float2bfloat16(oacc[m][nf][rr] / lrow[m][rr]);
      }
#undef STAGE_TILE
}

// ---------------------------------------------------------------------------
// Launch
// ---------------------------------------------------------------------------
extern "C" void kernel_launch(void* const* d_in, const int* in_sizes, int n_in,
                              void* d_out, int out_size, void* d_ws, size_t ws_size,
                              hipStream_t stream) {
  const float* x   = (const float*)d_in[0];
  const float* Wq  = (const float*)d_in[1];
  const float* Wk  = (const float*)d_in[2];
  const float* Wv  = (const float*)d_in[3];
  const float* Wo  = (const float*)d_in[4];
  const float* bo  = (const float*)d_in[5];
  const float* W1  = (const float*)d_in[6];
  const float* b1  = (const float*)d_in[7];
  const float* W2  = (const float*)d_in[8];
  const float* b2  = (const float*)d_in[9];
  const float* g1  = (const float*)d_in[10];
  const float* be1 = (const float*)d_in[11];
  const float* g2  = (const float*)d_in[12];
  const float* be2 = (const float*)d_in[13];

  char* ws = (char*)d_ws;
  const size_t MB = 1024 * 1024;
  __hip_bfloat16* hA    = (__hip_bfloat16*)(ws + 0);          // 16MB (LN1 out)
  __hip_bfloat16* attnO = (__hip_bfloat16*)(ws + 0);          // 16MB (reuse)
  __hip_bfloat16* qkv   = (__hip_bfloat16*)(ws + 16 * MB);    // 48MB
  float*          x2    = (float*)(ws + 16 * MB);             // 32MB (reuse qkv)
  __hip_bfloat16* h2    = (__hip_bfloat16*)(ws + 48 * MB);    // 16MB (reuse qkv tail)
  __hip_bfloat16* vtg   = (__hip_bfloat16*)(ws + 64 * MB);    // 16MB (dead after attn)
  __hip_bfloat16* act   = (__hip_bfloat16*)(ws + 64 * MB);    // 64MB (FFN1 out)
  __hip_bfloat16* WqkvT = (__hip_bfloat16*)(ws + 128 * MB);   // 6MB  [3072,1024]
  __hip_bfloat16* WoT   = (__hip_bfloat16*)(ws + 134 * MB);   // 2MB  [1024,1024]
  __hip_bfloat16* W1T   = (__hip_bfloat16*)(ws + 136 * MB);   // 8MB  [4096,1024]
  __hip_bfloat16* W2T   = (__hip_bfloat16*)(ws + 144 * MB);   // 8MB  [1024,4096]

  const dim3 tb(32, 8);
  tcvt_kernel<<<dim3(32, 32), tb, 0, stream>>>(Wq, WqkvT, 1024, 1024);
  tcvt_kernel<<<dim3(32, 32), tb, 0, stream>>>(Wk, WqkvT + 1024 * 1024, 1024, 1024);
  tcvt_kernel<<<dim3(32, 32), tb, 0, stream>>>(Wv, WqkvT + 2 * 1024 * 1024, 1024, 1024);
  tcvt_kernel<<<dim3(32, 32), tb, 0, stream>>>(Wo, WoT, 1024, 1024);
  tcvt_kernel<<<dim3(128, 32), tb, 0, stream>>>(W1, W1T, 1024, 4096);
  tcvt_kernel<<<dim3(32, 128), tb, 0, stream>>>(W2, W2T, 4096, 1024);

  ln_kernel<<<8192, 256, 0, stream>>>(x, g1, be1, hA);
  gemm256<0><<<dim3(32, 12), 512, 0, stream>>>(hA, WqkvT, qkv, nullptr, nullptr,
                                               3072, 1024);
  vtr_kernel<<<dim3(64, 2, 64), tb, 0, stream>>>(qkv, vtg);
  attn_kernel<<<1024, 256, 0, stream>>>(qkv, vtg, attnO);
  gemm256<1><<<dim3(32, 4), 512, 0, stream>>>(attnO, WoT, x2, bo, x, 1024, 1024);
  ln_kernel<<<8192, 256, 0, stream>>>(x2, g2, be2, h2);
  gemm256<2><<<dim3(32, 16), 512, 0, stream>>>(h2, W1T, act, b1, nullptr,
                                               4096, 1024);
  gemm256<1><<<dim3(32, 4), 512, 0, stream>>>(act, W2T, (float*)d_out, b2, x2,
                                              1024, 4096);
  (void)in_sizes; (void)n_in; (void)out_size; (void)ws_size;
}

// Round 6
// 466.349 us; speedup vs baseline: 1.1446x; 1.1446x over previous
//
#include <hip/hip_runtime.h>
#include <hip/hip_bf16.h>
#include <math.h>

// ---------------------------------------------------------------------------
// TransformerBlock on MI355X (gfx950).
// GEMMs: parameterized 2-phase counted-vmcnt schedule, st_16x32 LDS swizzle,
// tile shapes chosen for exact whole rounds of 256 CUs.
// Attn: round-4 LDS-staged double-buffered flash attention (unchanged).
// ---------------------------------------------------------------------------

typedef __attribute__((ext_vector_type(8))) short bf16x8;
typedef __attribute__((ext_vector_type(4))) float f32x4;

#define AS1 __attribute__((address_space(1)))
#define AS3 __attribute__((address_space(3)))

__device__ __forceinline__ void gl_lds16(const void* g, void* l) {
  __builtin_amdgcn_global_load_lds((const AS1 void*)g, (AS3 void*)l, 16, 0, 0);
}

__device__ __forceinline__ float gelu_f(float x) {
  const float c = 0.7978845608028654f;  // sqrt(2/pi)
  return 0.5f * x * (1.0f + tanhf(c * (x + 0.044715f * x * x * x)));
}

// ---------------------------------------------------------------------------
// Weight transpose + fp32->bf16 convert:  W [K,N] fp32  ->  WT [N,K] bf16
// ---------------------------------------------------------------------------
__global__ void __launch_bounds__(256) tcvt_kernel(
    const float* __restrict__ W, __hip_bfloat16* __restrict__ WT, int K, int N) {
  __shared__ float t[32][33];
  const int n0 = blockIdx.x * 32, k0 = blockIdx.y * 32;
  const int tx = threadIdx.x, ty0 = threadIdx.y;  // 32 x 8
#pragma unroll
  for (int i = 0; i < 4; i++) {
    int ty = ty0 + i * 8;
    t[ty][tx] = W[(size_t)(k0 + ty) * N + n0 + tx];
  }
  __syncthreads();
#pragma unroll
  for (int i = 0; i < 4; i++) {
    int ty = ty0 + i * 8;
    WT[(size_t)(n0 + ty) * K + k0 + tx] = __float2bfloat16(t[tx][ty]);
  }
}

// ---------------------------------------------------------------------------
// V transpose: qkv[b*2048+s][3072] (V at col 2048+h*64+hd) -> vt[(bh*64+hd)][s]
// ---------------------------------------------------------------------------
__global__ void __launch_bounds__(256) vtr_kernel(
    const __hip_bfloat16* __restrict__ qkv, __hip_bfloat16* __restrict__ vt) {
  __shared__ __hip_bfloat16 t[32][33];
  const int s0 = blockIdx.x * 32;
  const int hd0 = blockIdx.y * 32;
  const int bh = blockIdx.z;
  const int b = bh >> 4, h = bh & 15;
  const int tx = threadIdx.x, ty0 = threadIdx.y;  // 32 x 8
  const __hip_bfloat16* src =
      qkv + (size_t)(b * 2048 + s0) * 3072 + 2048 + h * 64 + hd0;
#pragma unroll
  for (int i = 0; i < 4; i++) {
    int ty = ty0 + i * 8;
    t[ty][tx] = src[(size_t)ty * 3072 + tx];  // t[s_local][hd_local]
  }
  __syncthreads();
  __hip_bfloat16* dst = vt + ((size_t)bh * 64 + hd0) * 2048 + s0;
#pragma unroll
  for (int i = 0; i < 4; i++) {
    int ty = ty0 + i * 8;
    dst[(size_t)ty * 2048 + tx] = t[tx][ty];
  }
}

// ---------------------------------------------------------------------------
// LayerNorm over D=1024, one block (256 thr) per row, fp32 in -> bf16 out
// ---------------------------------------------------------------------------
__global__ void __launch_bounds__(256) ln_kernel(
    const float* __restrict__ x, const float* __restrict__ gma,
    const float* __restrict__ bta, __hip_bfloat16* __restrict__ out) {
  const int row = blockIdx.x;
  const int tid = threadIdx.x;
  const float4 v = ((const float4*)(x + (size_t)row * 1024))[tid];
  float s = v.x + v.y + v.z + v.w;
  float s2 = v.x * v.x + v.y * v.y + v.z * v.z + v.w * v.w;
#pragma unroll
  for (int m = 32; m; m >>= 1) {
    s += __shfl_xor(s, m);
    s2 += __shfl_xor(s2, m);
  }
  __shared__ float red[8];
  const int w = tid >> 6, lane = tid & 63;
  if (lane == 0) { red[w] = s; red[4 + w] = s2; }
  __syncthreads();
  s = red[0] + red[1] + red[2] + red[3];
  s2 = red[4] + red[5] + red[6] + red[7];
  const float mu = s * (1.0f / 1024.0f);
  const float var = s2 * (1.0f / 1024.0f) - mu * mu;
  const float rs = rsqrtf(var + 1e-5f);
  const float4 gv = ((const float4*)gma)[tid];
  const float4 bv = ((const float4*)bta)[tid];
  __hip_bfloat16* orow = out + (size_t)row * 1024 + tid * 4;
  orow[0] = __float2bfloat16((v.x - mu) * rs * gv.x + bv.x);
  orow[1] = __float2bfloat16((v.y - mu) * rs * gv.y + bv.y);
  orow[2] = __float2bfloat16((v.z - mu) * rs * gv.z + bv.z);
  orow[3] = __float2bfloat16((v.w - mu) * rs * gv.w + bv.w);
}

// ---------------------------------------------------------------------------
// GEMM template: C = A[M,K] * B^T[N,K], bf16 in, fp32 acc. 512 thr, 8 waves
// (WM x WN), per-wave (BM/WM)x(BN/WN). BK=64 = 2 ks-halves of 32.
// Per K-tile: 2 phases {stage U units of tile t+1/t+2 -> vmcnt(3U) -> barrier
// -> MRxNR MFMA (setprio) -> barrier}. Loads never drained in-loop (T4).
// LDS [2buf][2ks][A BM rows x 64B | B BN rows x 64B]; st_16x32 swizzle:
// 16B slot ^= ((row>>3)&1)<<1 applied on BOTH gl_lds source and ds_read
// (involution, rule #21). Unit = 8KB = 128 rows staged by 512 thr x 16B.
// Ledger: prologue 3U = t0 ks0,ks1 + t1 ks0; ph0 stages (t+1,ks1), ph1
// stages (t+2,ks0); tail clamps re-stage already-consumed regions
// (idempotent, same buffer parity). vmcnt(0) drain before epilogue.
// EPI 0: bf16 | 1: fp32 = .+bias+resid | 2: bf16 = gelu(.+bias)
// ---------------------------------------------------------------------------
template <int BM, int BN, int WM, int WN, int EPI>
__global__ void __launch_bounds__(512, 2) gemmT(
    const __hip_bfloat16* __restrict__ Ap, const __hip_bfloat16* __restrict__ Bp,
    void* __restrict__ outp, const float* __restrict__ bias,
    const float* __restrict__ resid, int N, int K) {
  constexpr int PM = BM / WM, PN = BN / WN;   // per-wave tile
  constexpr int MR = PM / 16, NR = PN / 16;   // frags
  constexpr int UA = BM / 128, UB = BN / 128, U = UA + UB;
  constexpr int KSB = (BM + BN) * 64;         // bytes per ks region
  __shared__ __attribute__((aligned(128))) char smem[2 * 2 * KSB];
  const int tid = threadIdx.x;
  const int lane = tid & 63, w = tid >> 6;
  const int wr = w / WN, wc = w % WN;
  const int cr = lane & 15, g = lane >> 4;

  // XCD swizzle (grids all %8==0)
  const int nwg = gridDim.x * gridDim.y;
  const int orig = blockIdx.y * gridDim.x + blockIdx.x;
  const int swz = (orig & 7) * (nwg >> 3) + (orig >> 3);
  const int bm = swz % gridDim.x, bn = swz / gridDim.x;
  const int bmr = bm * BM, bnr = bn * BN;
  const int nkt = K >> 6;

  // staging map: thread -> (row in 128-row unit, swizzled 16B source slot)
  const int srow = tid >> 2;                                   // 0..127
  const int sq = ((tid & 3) ^ (((srow >> 3) & 1) << 1)) * 8;   // elems
  // read slot (row key = (cr>>3)&1 for all frags; PM,16 keep bit3 clear)
  const int rq = (g ^ (((cr >> 3) & 1) << 1)) * 8;             // elems

  auto stage_ks = [&](int tt, int ks) {
    char* base = smem + (tt & 1) * (2 * KSB) + ks * KSB;
#pragma unroll
    for (int ua = 0; ua < UA; ua++)
      gl_lds16(Ap + (size_t)(bmr + ua * 128 + srow) * K + tt * 64 + ks * 32 + sq,
               base + ua * 8192 + w * 1024);
#pragma unroll
    for (int ub = 0; ub < UB; ub++)
      gl_lds16(Bp + (size_t)(bnr + ub * 128 + srow) * K + tt * 64 + ks * 32 + sq,
               base + BM * 64 + ub * 8192 + w * 1024);
  };
  auto vmw = [&]() {
    if constexpr (U == 3)
      asm volatile("s_waitcnt vmcnt(9)" ::: "memory");
    else
      asm volatile("s_waitcnt vmcnt(12)" ::: "memory");
  };

  f32x4 acc[MR][NR];
#pragma unroll
  for (int i = 0; i < MR; i++)
#pragma unroll
    for (int j = 0; j < NR; j++) acc[i][j] = (f32x4){0.f, 0.f, 0.f, 0.f};

  auto compute = [&](int t, int ks) {
    const char* base = smem + (t & 1) * (2 * KSB) + ks * KSB;
    const __hip_bfloat16* pA = (const __hip_bfloat16*)base;
    const __hip_bfloat16* pB = (const __hip_bfloat16*)(base + BM * 64);
    bf16x8 av[MR], bv[NR];
#pragma unroll
    for (int m = 0; m < MR; m++)
      av[m] = *(const bf16x8*)(pA + (wr * PM + m * 16 + cr) * 32 + rq);
#pragma unroll
    for (int n = 0; n < NR; n++)
      bv[n] = *(const bf16x8*)(pB + (wc * PN + n * 16 + cr) * 32 + rq);
    __builtin_amdgcn_s_setprio(1);
#pragma unroll
    for (int m = 0; m < MR; m++)
#pragma unroll
      for (int n = 0; n < NR; n++)
        acc[m][n] =
            __builtin_amdgcn_mfma_f32_16x16x32_bf16(av[m], bv[n], acc[m][n], 0, 0, 0);
    __builtin_amdgcn_s_setprio(0);
  };

  // Prologue: 3U outstanding.
  stage_ks(0, 0);
  stage_ks(0, 1);
  stage_ks(1, 0);

  for (int t = 0; t < nkt; ++t) {
    stage_ks(t + 1 < nkt ? t + 1 : t - 1, 1);
    vmw();
    __builtin_amdgcn_s_barrier();
    compute(t, 0);
    __builtin_amdgcn_s_barrier();
    stage_ks(t + 2 < nkt ? t + 2 : t, 0);
    vmw();
    __builtin_amdgcn_s_barrier();
    compute(t, 1);
    __builtin_amdgcn_s_barrier();
  }
  asm volatile("s_waitcnt vmcnt(0)" ::: "memory");  // no in-flight LDS writes at exit

  // Epilogue. C/D layout: col = lane&15, row = (lane>>4)*4 + reg.
#pragma unroll
  for (int m = 0; m < MR; m++) {
#pragma unroll
    for (int rr = 0; rr < 4; rr++) {
      const int row = bmr + wr * PM + m * 16 + g * 4 + rr;
#pragma unroll
      for (int n = 0; n < NR; n++) {
        const int col = bnr + wc * PN + n * 16 + cr;
        float v = acc[m][n][rr];
        if (EPI == 0) {
          ((__hip_bfloat16*)outp)[(size_t)row * N + col] = __float2bfloat16(v);
        } else if (EPI == 1) {
          v += bias[col] + resid[(size_t)row * N + col];
          ((float*)outp)[(size_t)row * N + col] = v;
        } else {
          v = gelu_f(v + bias[col]);
          ((__hip_bfloat16*)outp)[(size_t)row * N + col] = __float2bfloat16(v);
        }
      }
    }
  }
}

// ---------------------------------------------------------------------------
// Flash attention, causal (round-4 version, unchanged). qkv [8192,3072] bf16,
// vt [bh][hd=64][s] bf16. 256 thr (4 waves), QBLK=128, KVBLK=64, dbuf LDS,
// XOR-swizzled staging, exp2-domain online softmax.
// ---------------------------------------------------------------------------
__global__ void __launch_bounds__(256) attn_kernel(
    const __hip_bfloat16* __restrict__ qkv, const __hip_bfloat16* __restrict__ vt,
    __hip_bfloat16* __restrict__ o) {
  __shared__ __hip_bfloat16 sK[2][64 * 64];   // [kv][hd], slot-swizzled
  __shared__ __hip_bfloat16 sV[2][64 * 64];   // [hd][kv], slot-swizzled
  __shared__ __hip_bfloat16 pl[4][16][64];    // per-wave P bounce, swizzled
  const int tid = threadIdx.x, lane = tid & 63, w = tid >> 6;
  const int bid = blockIdx.x;                  // 0..1023
  const int bh = (bid & 7) + 8 * ((bid >> 3) & 7);
  const int qt = 15 - (bid >> 6);              // heavy q-tiles first
  const int b = bh >> 4, h = bh & 15;
  const int cr = lane & 15, g = lane >> 4;
  const int qr0 = qt * 128 + w * 32;           // wave's first q row
  const float NEG = -1e30f;
  const float SC2 = 0.18033688011112042f;      // 0.125 * log2(e)
  const int sw = cr & 7;                       // read-side swizzle key
  const int sg0 = (g ^ sw) * 8;                // swizzled 16B slot (elems)
  const int sg1 = ((g ^ sw) ^ 4) * 8;

  bf16x8 aq[2][2];
#pragma unroll
  for (int m = 0; m < 2; m++) {
    const __hip_bfloat16* qp =
        qkv + (size_t)(b * 2048 + qr0 + m * 16 + cr) * 3072 + h * 64 + g * 8;
    aq[m][0] = *(const bf16x8*)qp;
    aq[m][1] = *(const bf16x8*)(qp + 32);
  }
  const __hip_bfloat16* kbase = qkv + (size_t)(b * 2048) * 3072 + 1024 + h * 64;
  const __hip_bfloat16* vbase = vt + (size_t)bh * 64 * 2048;

  const int l8 = lane >> 3, c8 = lane & 7;
  const int c8s = (c8 ^ l8) * 8;  // pre-swizzled global source slot (elems)
#define STAGE_TILE(bi, ktile)                                                   \
  {                                                                             \
    _Pragma("unroll") for (int i = 0; i < 2; i++) {                             \
      const int rb = (i * 4 + w) * 8 + l8;                                      \
      gl_lds16(kbase + (size_t)((ktile) * 64 + rb) * 3072 + c8s,                \
               &sK[bi][(i * 4 + w) * 512]);                                     \
      gl_lds16(vbase + (size_t)rb * 2048 + (ktile) * 64 + c8s,                  \
               &sV[bi][(i * 4 + w) * 512]);                                     \
    }                                                                           \
  }

  f32x4 oacc[2][4];
#pragma unroll
  for (int m = 0; m < 2; m++)
#pragma unroll
    for (int i = 0; i < 4; i++) oacc[m][i] = (f32x4){0.f, 0.f, 0.f, 0.f};
  float mrow[2][4], lrow[2][4];
#pragma unroll
  for (int m = 0; m < 2; m++)
#pragma unroll
    for (int rr = 0; rr < 4; rr++) { mrow[m][rr] = NEG; lrow[m][rr] = 0.f; }

  const int nkt = (qt + 1) * 2;
  STAGE_TILE(0, 0);
  asm volatile("s_waitcnt vmcnt(0)" ::: "memory");
  __syncthreads();
  int cur = 0;

  for (int kt = 0; kt < nkt; ++kt) {
    if (kt + 1 < nkt) STAGE_TILE(cur ^ 1, kt + 1);

    if (kt * 64 <= qr0 + 31) {
      f32x4 s[2][4];
      __builtin_amdgcn_s_setprio(1);
#pragma unroll
      for (int nf = 0; nf < 4; nf++) {
        const bf16x8 bk0 = *(const bf16x8*)&sK[cur][(nf * 16 + cr) * 64 + sg0];
        const bf16x8 bk1 = *(const bf16x8*)&sK[cur][(nf * 16 + cr) * 64 + sg1];
#pragma unroll
        for (int m = 0; m < 2; m++) {
          f32x4 z = (f32x4){0.f, 0.f, 0.f, 0.f};
          z = __builtin_amdgcn_mfma_f32_16x16x32_bf16(aq[m][0], bk0, z, 0, 0, 0);
          z = __builtin_amdgcn_mfma_f32_16x16x32_bf16(aq[m][1], bk1, z, 0, 0, 0);
          s[m][nf] = z * SC2;
        }
      }
      __builtin_amdgcn_s_setprio(0);
      if (kt * 64 + 63 > qr0) {
#pragma unroll
        for (int m = 0; m < 2; m++)
#pragma unroll
          for (int nf = 0; nf < 4; nf++)
#pragma unroll
            for (int rr = 0; rr < 4; rr++) {
              const int kvcol = kt * 64 + nf * 16 + cr;
              const int qrow = qr0 + m * 16 + g * 4 + rr;
              if (kvcol > qrow) s[m][nf][rr] = NEG;
            }
      }
#pragma unroll
      for (int m = 0; m < 2; m++) {
        float scl[4];
#pragma unroll
        for (int rr = 0; rr < 4; rr++) {
          float v = fmaxf(fmaxf(s[m][0][rr], s[m][1][rr]),
                          fmaxf(s[m][2][rr], s[m][3][rr]));
          v = fmaxf(v, __shfl_xor(v, 1));
          v = fmaxf(v, __shfl_xor(v, 2));
          v = fmaxf(v, __shfl_xor(v, 4));
          v = fmaxf(v, __shfl_xor(v, 8));
          const float mn = fmaxf(mrow[m][rr], v);
          scl[rr] = exp2f(mrow[m][rr] - mn);
          mrow[m][rr] = mn;
        }
        float rsum[4] = {0.f, 0.f, 0.f, 0.f};
#pragma unroll
        for (int nf = 0; nf < 4; nf++)
#pragma unroll
          for (int rr = 0; rr < 4; rr++) {
            const float p = exp2f(s[m][nf][rr] - mrow[m][rr]);
            s[m][nf][rr] = p;
            rsum[rr] += p;
          }
#pragma unroll
        for (int rr = 0; rr < 4; rr++) {
          float v = rsum[rr];
          v += __shfl_xor(v, 1);
          v += __shfl_xor(v, 2);
          v += __shfl_xor(v, 4);
          v += __shfl_xor(v, 8);
          lrow[m][rr] = lrow[m][rr] * scl[rr] + v;
        }
#pragma unroll
        for (int nf = 0; nf < 4; nf++) {
          f32x4 t = oacc[m][nf];
          t[0] *= scl[0]; t[1] *= scl[1]; t[2] *= scl[2]; t[3] *= scl[3];
          oacc[m][nf] = t;
        }
#pragma unroll
        for (int nf = 0; nf < 4; nf++)
#pragma unroll
          for (int rr = 0; rr < 4; rr++) {
            const int prow = g * 4 + rr;
            pl[w][prow][(nf * 16 + cr) ^ ((prow & 7) << 3)] =
                __float2bfloat16(s[m][nf][rr]);
          }
        const bf16x8 pa0 = *(const bf16x8*)&pl[w][cr][sg0];
        const bf16x8 pa1 = *(const bf16x8*)&pl[w][cr][sg1];
        __builtin_amdgcn_s_setprio(1);
#pragma unroll
        for (int nf = 0; nf < 4; nf++) {
          const bf16x8 bv0 = *(const bf16x8*)&sV[cur][(nf * 16 + cr) * 64 + sg0];
          const bf16x8 bv1 = *(const bf16x8*)&sV[cur][(nf * 16 + cr) * 64 + sg1];
          oacc[m][nf] = __builtin_amdgcn_mfma_f32_16x16x32_bf16(pa0, bv0, oacc[m][nf], 0, 0, 0);
          oacc[m][nf] = __builtin_amdgcn_mfma_f32_16x16x32_bf16(pa1, bv1, oacc[m][nf], 0, 0, 0);
        }
        __builtin_amdgcn_s_setprio(0);
      }
    }

    if (kt + 1 < nkt) {
      asm volatile("s_waitcnt vmcnt(0)" ::: "memory");
      __syncthreads();
      cur ^= 1;
    }
  }

#pragma unroll
  for (int m = 0; m < 2; m++)
#pragma unroll
    for (int nf = 0; nf < 4; nf++)
#pragma unroll
      for (int rr = 0; rr < 4; rr++) {
        const int row = qr0 + m * 16 + g * 4 + rr;
        o[(size_t)(b * 2048 + row) * 1024 + h * 64 + nf * 16 + cr] =
            __float2bfloat16(oacc[m][nf][rr] / lrow[m][rr]);
      }
#undef STAGE_TILE
}

// ---------------------------------------------------------------------------
// Launch
// ---------------------------------------------------------------------------
extern "C" void kernel_launch(void* const* d_in, const int* in_sizes, int n_in,
                              void* d_out, int out_size, void* d_ws, size_t ws_size,
                              hipStream_t stream) {
  const float* x   = (const float*)d_in[0];
  const float* Wq  = (const float*)d_in[1];
  const float* Wk  = (const float*)d_in[2];
  const float* Wv  = (const float*)d_in[3];
  const float* Wo  = (const float*)d_in[4];
  const float* bo  = (const float*)d_in[5];
  const float* W1  = (const float*)d_in[6];
  const float* b1  = (const float*)d_in[7];
  const float* W2  = (const float*)d_in[8];
  const float* b2  = (const float*)d_in[9];
  const float* g1  = (const float*)d_in[10];
  const float* be1 = (const float*)d_in[11];
  const float* g2  = (const float*)d_in[12];
  const float* be2 = (const float*)d_in[13];

  char* ws = (char*)d_ws;
  const size_t MB = 1024 * 1024;
  __hip_bfloat16* hA    = (__hip_bfloat16*)(ws + 0);          // 16MB (LN1 out)
  __hip_bfloat16* attnO = (__hip_bfloat16*)(ws + 0);          // 16MB (reuse)
  __hip_bfloat16* qkv   = (__hip_bfloat16*)(ws + 16 * MB);    // 48MB
  float*          x2    = (float*)(ws + 16 * MB);             // 32MB (reuse qkv)
  __hip_bfloat16* h2    = (__hip_bfloat16*)(ws + 48 * MB);    // 16MB (reuse qkv tail)
  __hip_bfloat16* vtg   = (__hip_bfloat16*)(ws + 64 * MB);    // 16MB (dead after attn)
  __hip_bfloat16* act   = (__hip_bfloat16*)(ws + 64 * MB);    // 64MB (FFN1 out)
  __hip_bfloat16* WqkvT = (__hip_bfloat16*)(ws + 128 * MB);   // 6MB  [3072,1024]
  __hip_bfloat16* WoT   = (__hip_bfloat16*)(ws + 134 * MB);   // 2MB  [1024,1024]
  __hip_bfloat16* W1T   = (__hip_bfloat16*)(ws + 136 * MB);   // 8MB  [4096,1024]
  __hip_bfloat16* W2T   = (__hip_bfloat16*)(ws + 144 * MB);   // 8MB  [1024,4096]

  const dim3 tb(32, 8);
  tcvt_kernel<<<dim3(32, 32), tb, 0, stream>>>(Wq, WqkvT, 1024, 1024);
  tcvt_kernel<<<dim3(32, 32), tb, 0, stream>>>(Wk, WqkvT + 1024 * 1024, 1024, 1024);
  tcvt_kernel<<<dim3(32, 32), tb, 0, stream>>>(Wv, WqkvT + 2 * 1024 * 1024, 1024, 1024);
  tcvt_kernel<<<dim3(32, 32), tb, 0, stream>>>(Wo, WoT, 1024, 1024);
  tcvt_kernel<<<dim3(128, 32), tb, 0, stream>>>(W1, W1T, 1024, 4096);
  tcvt_kernel<<<dim3(32, 128), tb, 0, stream>>>(W2, W2T, 4096, 1024);

  ln_kernel<<<8192, 256, 0, stream>>>(x, g1, be1, hA);
  // QKV: M=8192,N=3072,K=1024 -> 64x12 = 768 blocks (3.0 rounds)
  gemmT<128, 256, 2, 4, 0><<<dim3(64, 12), 512, 0, stream>>>(
      hA, WqkvT, qkv, nullptr, nullptr, 3072, 1024);
  vtr_kernel<<<dim3(64, 2, 64), tb, 0, stream>>>(qkv, vtg);
  attn_kernel<<<1024, 256, 0, stream>>>(qkv, vtg, attnO);
  // O-proj: N=1024 -> 64x4 = 256 blocks (1.0 round)
  gemmT<128, 256, 2, 4, 1><<<dim3(64, 4), 512, 0, stream>>>(
      attnO, WoT, x2, bo, x, 1024, 1024);
  ln_kernel<<<8192, 256, 0, stream>>>(x2, g2, be2, h2);
  // FFN1: N=4096 -> 32x16 = 512 blocks (2.0 rounds)
  gemmT<256, 256, 2, 4, 2><<<dim3(32, 16), 512, 0, stream>>>(
      h2, W1T, act, b1, nullptr, 4096, 1024);
  // FFN2: N=1024, K=4096 -> 64x4 = 256 blocks (1.0 round)
  gemmT<128, 256, 2, 4, 1><<<dim3(64, 4), 512, 0, stream>>>(
      act, W2T, (float*)d_out, b2, x2, 1024, 4096);
  (void)in_sizes; (void)n_in; (void)out_size; (void)ws_size;
}

// Round 8
// 414.982 us; speedup vs baseline: 1.2863x; 1.1238x over previous
//
#include <hip/hip_runtime.h>
#include <hip/hip_bf16.h>
#include <math.h>

// ---------------------------------------------------------------------------
// TransformerBlock on MI355X (gfx950).
// GEMMs: parameterized 2-phase counted-vmcnt schedule, st_16x32 LDS swizzle,
// tile shapes chosen for exact whole rounds of 256 CUs. (unchanged R6)
// Attn: swapped-QK^T in-register softmax (q lane-local), defer-max rescale,
// packed b64 P-bounce. K/V staging + PV unchanged from R4.
// ---------------------------------------------------------------------------

typedef __attribute__((ext_vector_type(8))) short bf16x8;
typedef __attribute__((ext_vector_type(4))) float f32x4;

#define AS1 __attribute__((address_space(1)))
#define AS3 __attribute__((address_space(3)))

__device__ __forceinline__ void gl_lds16(const void* g, void* l) {
  __builtin_amdgcn_global_load_lds((const AS1 void*)g, (AS3 void*)l, 16, 0, 0);
}

__device__ __forceinline__ float gelu_f(float x) {
  const float c = 0.7978845608028654f;  // sqrt(2/pi)
  return 0.5f * x * (1.0f + tanhf(c * (x + 0.044715f * x * x * x)));
}

__device__ __forceinline__ float bf2f(short s) {
  unsigned u = ((unsigned)(unsigned short)s) << 16;
  return __builtin_bit_cast(float, u);
}
__device__ __forceinline__ short f2bf(float f) {
  __hip_bfloat16 h = __float2bfloat16(f);
  return __builtin_bit_cast(short, h);
}

// ---------------------------------------------------------------------------
// Weight transpose + fp32->bf16 convert:  W [K,N] fp32  ->  WT [N,K] bf16
// ---------------------------------------------------------------------------
__global__ void __launch_bounds__(256) tcvt_kernel(
    const float* __restrict__ W, __hip_bfloat16* __restrict__ WT, int K, int N) {
  __shared__ float t[32][33];
  const int n0 = blockIdx.x * 32, k0 = blockIdx.y * 32;
  const int tx = threadIdx.x, ty0 = threadIdx.y;  // 32 x 8
#pragma unroll
  for (int i = 0; i < 4; i++) {
    int ty = ty0 + i * 8;
    t[ty][tx] = W[(size_t)(k0 + ty) * N + n0 + tx];
  }
  __syncthreads();
#pragma unroll
  for (int i = 0; i < 4; i++) {
    int ty = ty0 + i * 8;
    WT[(size_t)(n0 + ty) * K + k0 + tx] = __float2bfloat16(t[tx][ty]);
  }
}

// ---------------------------------------------------------------------------
// V transpose: qkv[b*2048+s][3072] (V at col 2048+h*64+hd) -> vt[(bh*64+hd)][s]
// ---------------------------------------------------------------------------
__global__ void __launch_bounds__(256) vtr_kernel(
    const __hip_bfloat16* __restrict__ qkv, __hip_bfloat16* __restrict__ vt) {
  __shared__ __hip_bfloat16 t[32][33];
  const int s0 = blockIdx.x * 32;
  const int hd0 = blockIdx.y * 32;
  const int bh = blockIdx.z;
  const int b = bh >> 4, h = bh & 15;
  const int tx = threadIdx.x, ty0 = threadIdx.y;  // 32 x 8
  const __hip_bfloat16* src =
      qkv + (size_t)(b * 2048 + s0) * 3072 + 2048 + h * 64 + hd0;
#pragma unroll
  for (int i = 0; i < 4; i++) {
    int ty = ty0 + i * 8;
    t[ty][tx] = src[(size_t)ty * 3072 + tx];  // t[s_local][hd_local]
  }
  __syncthreads();
  __hip_bfloat16* dst = vt + ((size_t)bh * 64 + hd0) * 2048 + s0;
#pragma unroll
  for (int i = 0; i < 4; i++) {
    int ty = ty0 + i * 8;
    dst[(size_t)ty * 2048 + tx] = t[tx][ty];
  }
}

// ---------------------------------------------------------------------------
// LayerNorm over D=1024, one block (256 thr) per row, fp32 in -> bf16 out
// ---------------------------------------------------------------------------
__global__ void __launch_bounds__(256) ln_kernel(
    const float* __restrict__ x, const float* __restrict__ gma,
    const float* __restrict__ bta, __hip_bfloat16* __restrict__ out) {
  const int row = blockIdx.x;
  const int tid = threadIdx.x;
  const float4 v = ((const float4*)(x + (size_t)row * 1024))[tid];
  float s = v.x + v.y + v.z + v.w;
  float s2 = v.x * v.x + v.y * v.y + v.z * v.z + v.w * v.w;
#pragma unroll
  for (int m = 32; m; m >>= 1) {
    s += __shfl_xor(s, m);
    s2 += __shfl_xor(s2, m);
  }
  __shared__ float red[8];
  const int w = tid >> 6, lane = tid & 63;
  if (lane == 0) { red[w] = s; red[4 + w] = s2; }
  __syncthreads();
  s = red[0] + red[1] + red[2] + red[3];
  s2 = red[4] + red[5] + red[6] + red[7];
  const float mu = s * (1.0f / 1024.0f);
  const float var = s2 * (1.0f / 1024.0f) - mu * mu;
  const float rs = rsqrtf(var + 1e-5f);
  const float4 gv = ((const float4*)gma)[tid];
  const float4 bv = ((const float4*)bta)[tid];
  __hip_bfloat16* orow = out + (size_t)row * 1024 + tid * 4;
  orow[0] = __float2bfloat16((v.x - mu) * rs * gv.x + bv.x);
  orow[1] = __float2bfloat16((v.y - mu) * rs * gv.y + bv.y);
  orow[2] = __float2bfloat16((v.z - mu) * rs * gv.z + bv.z);
  orow[3] = __float2bfloat16((v.w - mu) * rs * gv.w + bv.w);
}

// ---------------------------------------------------------------------------
// GEMM template (unchanged from R6): 2-phase counted-vmcnt, st_16x32 swizzle.
// ---------------------------------------------------------------------------
template <int BM, int BN, int WM, int WN, int EPI>
__global__ void __launch_bounds__(512, 2) gemmT(
    const __hip_bfloat16* __restrict__ Ap, const __hip_bfloat16* __restrict__ Bp,
    void* __restrict__ outp, const float* __restrict__ bias,
    const float* __restrict__ resid, int N, int K) {
  constexpr int PM = BM / WM, PN = BN / WN;   // per-wave tile
  constexpr int MR = PM / 16, NR = PN / 16;   // frags
  constexpr int UA = BM / 128, UB = BN / 128, U = UA + UB;
  constexpr int KSB = (BM + BN) * 64;         // bytes per ks region
  __shared__ __attribute__((aligned(128))) char smem[2 * 2 * KSB];
  const int tid = threadIdx.x;
  const int lane = tid & 63, w = tid >> 6;
  const int wr = w / WN, wc = w % WN;
  const int cr = lane & 15, g = lane >> 4;

  const int nwg = gridDim.x * gridDim.y;
  const int orig = blockIdx.y * gridDim.x + blockIdx.x;
  const int swz = (orig & 7) * (nwg >> 3) + (orig >> 3);
  const int bm = swz % gridDim.x, bn = swz / gridDim.x;
  const int bmr = bm * BM, bnr = bn * BN;
  const int nkt = K >> 6;

  const int srow = tid >> 2;                                   // 0..127
  const int sq = ((tid & 3) ^ (((srow >> 3) & 1) << 1)) * 8;   // elems
  const int rq = (g ^ (((cr >> 3) & 1) << 1)) * 8;             // elems

  auto stage_ks = [&](int tt, int ks) {
    char* base = smem + (tt & 1) * (2 * KSB) + ks * KSB;
#pragma unroll
    for (int ua = 0; ua < UA; ua++)
      gl_lds16(Ap + (size_t)(bmr + ua * 128 + srow) * K + tt * 64 + ks * 32 + sq,
               base + ua * 8192 + w * 1024);
#pragma unroll
    for (int ub = 0; ub < UB; ub++)
      gl_lds16(Bp + (size_t)(bnr + ub * 128 + srow) * K + tt * 64 + ks * 32 + sq,
               base + BM * 64 + ub * 8192 + w * 1024);
  };
  auto vmw = [&]() {
    if constexpr (U == 3)
      asm volatile("s_waitcnt vmcnt(9)" ::: "memory");
    else
      asm volatile("s_waitcnt vmcnt(12)" ::: "memory");
  };

  f32x4 acc[MR][NR];
#pragma unroll
  for (int i = 0; i < MR; i++)
#pragma unroll
    for (int j = 0; j < NR; j++) acc[i][j] = (f32x4){0.f, 0.f, 0.f, 0.f};

  auto compute = [&](int t, int ks) {
    const char* base = smem + (t & 1) * (2 * KSB) + ks * KSB;
    const __hip_bfloat16* pA = (const __hip_bfloat16*)base;
    const __hip_bfloat16* pB = (const __hip_bfloat16*)(base + BM * 64);
    bf16x8 av[MR], bv[NR];
#pragma unroll
    for (int m = 0; m < MR; m++)
      av[m] = *(const bf16x8*)(pA + (wr * PM + m * 16 + cr) * 32 + rq);
#pragma unroll
    for (int n = 0; n < NR; n++)
      bv[n] = *(const bf16x8*)(pB + (wc * PN + n * 16 + cr) * 32 + rq);
    __builtin_amdgcn_s_setprio(1);
#pragma unroll
    for (int m = 0; m < MR; m++)
#pragma unroll
      for (int n = 0; n < NR; n++)
        acc[m][n] =
            __builtin_amdgcn_mfma_f32_16x16x32_bf16(av[m], bv[n], acc[m][n], 0, 0, 0);
    __builtin_amdgcn_s_setprio(0);
  };

  stage_ks(0, 0);
  stage_ks(0, 1);
  stage_ks(1, 0);

  for (int t = 0; t < nkt; ++t) {
    stage_ks(t + 1 < nkt ? t + 1 : t - 1, 1);
    vmw();
    __builtin_amdgcn_s_barrier();
    compute(t, 0);
    __builtin_amdgcn_s_barrier();
    stage_ks(t + 2 < nkt ? t + 2 : t, 0);
    vmw();
    __builtin_amdgcn_s_barrier();
    compute(t, 1);
    __builtin_amdgcn_s_barrier();
  }
  asm volatile("s_waitcnt vmcnt(0)" ::: "memory");

#pragma unroll
  for (int m = 0; m < MR; m++) {
#pragma unroll
    for (int rr = 0; rr < 4; rr++) {
      const int row = bmr + wr * PM + m * 16 + g * 4 + rr;
#pragma unroll
      for (int n = 0; n < NR; n++) {
        const int col = bnr + wc * PN + n * 16 + cr;
        float v = acc[m][n][rr];
        if (EPI == 0) {
          ((__hip_bfloat16*)outp)[(size_t)row * N + col] = __float2bfloat16(v);
        } else if (EPI == 1) {
          v += bias[col] + resid[(size_t)row * N + col];
          ((float*)outp)[(size_t)row * N + col] = v;
        } else {
          v = gelu_f(v + bias[col]);
          ((__hip_bfloat16*)outp)[(size_t)row * N + col] = __float2bfloat16(v);
        }
      }
    }
  }
}

// ---------------------------------------------------------------------------
// Flash attention, causal. qkv [8192,3072] bf16 (Q|K|V), vt [bh][hd=64][s].
// 256 thr (4 waves), QBLK=128 (wave owns 32 q), KVBLK=64, dbuf LDS staging
// (unchanged). Swapped QK^T -> S^T (k rows, q cols): softmax reduce is
// 15 in-reg + 2 shfl per m-frag; defer-max rescale (exp2 THR=8, wave-
// uniform); P^T packed as 4x ds_write_b64 with even-key XOR swizzle
// (b128-read-compatible involution); Q pre-scaled by 0.125*log2e at load.
// ---------------------------------------------------------------------------
__global__ void __launch_bounds__(256) attn_kernel(
    const __hip_bfloat16* __restrict__ qkv, const __hip_bfloat16* __restrict__ vt,
    __hip_bfloat16* __restrict__ o) {
  __shared__ __hip_bfloat16 sK[2][64 * 64];   // [kv][hd], slot-swizzled
  __shared__ __hip_bfloat16 sV[2][64 * 64];   // [hd][kv], slot-swizzled
  __shared__ __hip_bfloat16 pl[4][16][64];    // per-wave P^T bounce, swizzled
  const int tid = threadIdx.x, lane = tid & 63, w = tid >> 6;
  const int bid = blockIdx.x;                  // 0..1023
  const int bh = (bid & 7) + 8 * ((bid >> 3) & 7);
  const int qt = 15 - (bid >> 6);              // heavy q-tiles first
  const int b = bh >> 4, h = bh & 15;
  const int cr = lane & 15, g = lane >> 4;
  const int qr0 = qt * 128 + w * 32;           // wave's first q row
  const float NEG = -1e30f;
  const float SC2 = 0.18033688011112042f;      // 0.125 * log2(e)
  const int sw = cr & 7;                       // K/V read swizzle key
  const int sg0 = (g ^ sw) * 8;
  const int sg1 = ((g ^ sw) ^ 4) * 8;
  const int pkey = (cr & 7) << 1;              // P bounce swizzle key (even)

  // Q fragments, pre-scaled by SC2 (B-operand: col=lane&15=q, k=g*8+j)
  bf16x8 aq[2][2];
#pragma unroll
  for (int m = 0; m < 2; m++) {
    const __hip_bfloat16* qp =
        qkv + (size_t)(b * 2048 + qr0 + m * 16 + cr) * 3072 + h * 64 + g * 8;
    bf16x8 q0 = *(const bf16x8*)qp;
    bf16x8 q1 = *(const bf16x8*)(qp + 32);
#pragma unroll
    for (int j = 0; j < 8; j++) {
      aq[m][0][j] = f2bf(bf2f(q0[j]) * SC2);
      aq[m][1][j] = f2bf(bf2f(q1[j]) * SC2);
    }
  }
  const __hip_bfloat16* kbase = qkv + (size_t)(b * 2048) * 3072 + 1024 + h * 64;
  const __hip_bfloat16* vbase = vt + (size_t)bh * 64 * 2048;

  const int l8 = lane >> 3, c8 = lane & 7;
  const int c8s = (c8 ^ l8) * 8;  // pre-swizzled global source slot (elems)
#define STAGE_TILE(bi, ktile)                                                   \
  {                                                                             \
    _Pragma("unroll") for (int i = 0; i < 2; i++) {                             \
      const int rb = (i * 4 + w) * 8 + l8;                                      \
      gl_lds16(kbase + (size_t)((ktile) * 64 + rb) * 3072 + c8s,                \
               &sK[bi][(i * 4 + w) * 512]);                                     \
      gl_lds16(vbase + (size_t)rb * 2048 + (ktile) * 64 + c8s,                  \
               &sV[bi][(i * 4 + w) * 512]);                                     \
    }                                                                           \
  }

  f32x4 oacc[2][4];
#pragma unroll
  for (int m = 0; m < 2; m++)
#pragma unroll
    for (int i = 0; i < 4; i++) oacc[m][i] = (f32x4){0.f, 0.f, 0.f, 0.f};
  float mrow[2] = {NEG, NEG};   // per-lane: q = qr0 + m*16 + cr
  float lrow[2] = {0.f, 0.f};

  const int nkt = (qt + 1) * 2;
  STAGE_TILE(0, 0);
  asm volatile("s_waitcnt vmcnt(0)" ::: "memory");
  __syncthreads();
  int cur = 0;

  for (int kt = 0; kt < nkt; ++kt) {
    if (kt + 1 < nkt) STAGE_TILE(cur ^ 1, kt + 1);

    if (kt * 64 <= qr0 + 31) {
      // ---- S^T = (K Q^T): rows k (kf,g,rr), cols q (cr) ----
      f32x4 st[4][2];  // [kf][mq]
      __builtin_amdgcn_s_setprio(1);
#pragma unroll
      for (int kf = 0; kf < 4; kf++) {
        const bf16x8 bk0 = *(const bf16x8*)&sK[cur][(kf * 16 + cr) * 64 + sg0];
        const bf16x8 bk1 = *(const bf16x8*)&sK[cur][(kf * 16 + cr) * 64 + sg1];
#pragma unroll
        for (int mq = 0; mq < 2; mq++) {
          f32x4 z = (f32x4){0.f, 0.f, 0.f, 0.f};
          z = __builtin_amdgcn_mfma_f32_16x16x32_bf16(bk0, aq[mq][0], z, 0, 0, 0);
          z = __builtin_amdgcn_mfma_f32_16x16x32_bf16(bk1, aq[mq][1], z, 0, 0, 0);
          st[kf][mq] = z;
        }
      }
      __builtin_amdgcn_s_setprio(0);
      // ---- causal mask (diagonal region only) ----
      if (kt * 64 + 63 > qr0) {
#pragma unroll
        for (int kf = 0; kf < 4; kf++)
#pragma unroll
          for (int mq = 0; mq < 2; mq++)
#pragma unroll
            for (int rr = 0; rr < 4; rr++) {
              const int kvcol = kt * 64 + kf * 16 + g * 4 + rr;
              const int qrow = qr0 + mq * 16 + cr;
              if (kvcol > qrow) st[kf][mq][rr] = NEG;
            }
      }
      // ---- per mq: in-register online softmax + packed P bounce + PV ----
#pragma unroll
      for (int mq = 0; mq < 2; mq++) {
        float pmax = st[0][mq][0];
#pragma unroll
        for (int kf = 0; kf < 4; kf++)
#pragma unroll
          for (int rr = 0; rr < 4; rr++)
            pmax = fmaxf(pmax, st[kf][mq][rr]);
        pmax = fmaxf(pmax, __shfl_xor(pmax, 16));
        pmax = fmaxf(pmax, __shfl_xor(pmax, 32));
        // defer-max: rescale only when wave-wide growth exceeds THR=8 (exp2)
        if (__any(pmax > mrow[mq] + 8.0f)) {
          const float mn = fmaxf(mrow[mq], pmax);
          const float scl = exp2f(mrow[mq] - mn);
          mrow[mq] = mn;
          lrow[mq] *= scl;
          float s0 = __shfl(scl, g * 4 + 0);
          float s1 = __shfl(scl, g * 4 + 1);
          float s2 = __shfl(scl, g * 4 + 2);
          float s3 = __shfl(scl, g * 4 + 3);
#pragma unroll
          for (int nf = 0; nf < 4; nf++) {
            f32x4 t = oacc[mq][nf];
            t[0] *= s0; t[1] *= s1; t[2] *= s2; t[3] *= s3;
            oacc[mq][nf] = t;
          }
        }
        float rsum = 0.f;
#pragma unroll
        for (int kf = 0; kf < 4; kf++) {
          short4 pk;
#pragma unroll
          for (int rr = 0; rr < 4; rr++) {
            const float p = exp2f(st[kf][mq][rr] - mrow[mq]);
            rsum += p;
            ((short*)&pk)[rr] = f2bf(p);
          }
          const int slot4 = (kf * 4 + g) ^ pkey;
          *(short4*)&pl[w][cr][slot4 * 4] = pk;
        }
        rsum += __shfl_xor(rsum, 16);
        rsum += __shfl_xor(rsum, 32);
        lrow[mq] += rsum;
        // ---- PV: pa from swizzled bounce, bv from sV (unchanged layout) ----
        const bf16x8 pa0 = *(const bf16x8*)&pl[w][cr][((2 * g) ^ pkey) * 4];
        const bf16x8 pa1 = *(const bf16x8*)&pl[w][cr][((2 * g + 8) ^ pkey) * 4];
        __builtin_amdgcn_s_setprio(1);
#pragma unroll
        for (int nf = 0; nf < 4; nf++) {
          const bf16x8 bv0 = *(const bf16x8*)&sV[cur][(nf * 16 + cr) * 64 + sg0];
          const bf16x8 bv1 = *(const bf16x8*)&sV[cur][(nf * 16 + cr) * 64 + sg1];
          oacc[mq][nf] = __builtin_amdgcn_mfma_f32_16x16x32_bf16(pa0, bv0, oacc[mq][nf], 0, 0, 0);
          oacc[mq][nf] = __builtin_amdgcn_mfma_f32_16x16x32_bf16(pa1, bv1, oacc[mq][nf], 0, 0, 0);
        }
        __builtin_amdgcn_s_setprio(0);
      }
    }

    if (kt + 1 < nkt) {
      asm volatile("s_waitcnt vmcnt(0)" ::: "memory");
      __syncthreads();
      cur ^= 1;
    }
  }

  // ---- write O: gather per-row denominators from lane cr = row ----
#pragma unroll
  for (int m = 0; m < 2; m++) {
    float il[4];
#pragma unroll
    for (int rr = 0; rr < 4; rr++)
      il[rr] = 1.0f / __shfl(lrow[m], g * 4 + rr);
#pragma unroll
    for (int nf = 0; nf < 4; nf++)
#pragma unroll
      for (int rr = 0; rr < 4; rr++) {
        const int row = qr0 + m * 16 + g * 4 + rr;
        o[(size_t)(b * 2048 + row) * 1024 + h * 64 + nf * 16 + cr] =
            __float2bfloat16(oacc[m][nf][rr] * il[rr]);
      }
  }
#undef STAGE_TILE
}

// ---------------------------------------------------------------------------
// Launch
// ---------------------------------------------------------------------------
extern "C" void kernel_launch(void* const* d_in, const int* in_sizes, int n_in,
                              void* d_out, int out_size, void* d_ws, size_t ws_size,
                              hipStream_t stream) {
  const float* x   = (const float*)d_in[0];
  const float* Wq  = (const float*)d_in[1];
  const float* Wk  = (const float*)d_in[2];
  const float* Wv  = (const float*)d_in[3];
  const float* Wo  = (const float*)d_in[4];
  const float* bo  = (const float*)d_in[5];
  const float* W1  = (const float*)d_in[6];
  const float* b1  = (const float*)d_in[7];
  const float* W2  = (const float*)d_in[8];
  const float* b2  = (const float*)d_in[9];
  const float* g1  = (const float*)d_in[10];
  const float* be1 = (const float*)d_in[11];
  const float* g2  = (const float*)d_in[12];
  const float* be2 = (const float*)d_in[13];

  char* ws = (char*)d_ws;
  const size_t MB = 1024 * 1024;
  __hip_bfloat16* hA    = (__hip_bfloat16*)(ws + 0);          // 16MB (LN1 out)
  __hip_bfloat16* attnO = (__hip_bfloat16*)(ws + 0);          // 16MB (reuse)
  __hip_bfloat16* qkv   = (__hip_bfloat16*)(ws + 16 * MB);    // 48MB
  float*          x2    = (float*)(ws + 16 * MB);             // 32MB (reuse qkv)
  __hip_bfloat16* h2    = (__hip_bfloat16*)(ws + 48 * MB);    // 16MB (reuse qkv tail)
  __hip_bfloat16* vtg   = (__hip_bfloat16*)(ws + 64 * MB);    // 16MB (dead after attn)
  __hip_bfloat16* act   = (__hip_bfloat16*)(ws + 64 * MB);    // 64MB (FFN1 out)
  __hip_bfloat16* WqkvT = (__hip_bfloat16*)(ws + 128 * MB);   // 6MB  [3072,1024]
  __hip_bfloat16* WoT   = (__hip_bfloat16*)(ws + 134 * MB);   // 2MB  [1024,1024]
  __hip_bfloat16* W1T   = (__hip_bfloat16*)(ws + 136 * MB);   // 8MB  [4096,1024]
  __hip_bfloat16* W2T   = (__hip_bfloat16*)(ws + 144 * MB);   // 8MB  [1024,4096]

  const dim3 tb(32, 8);
  tcvt_kernel<<<dim3(32, 32), tb, 0, stream>>>(Wq, WqkvT, 1024, 1024);
  tcvt_kernel<<<dim3(32, 32), tb, 0, stream>>>(Wk, WqkvT + 1024 * 1024, 1024, 1024);
  tcvt_kernel<<<dim3(32, 32), tb, 0, stream>>>(Wv, WqkvT + 2 * 1024 * 1024, 1024, 1024);
  tcvt_kernel<<<dim3(32, 32), tb, 0, stream>>>(Wo, WoT, 1024, 1024);
  tcvt_kernel<<<dim3(128, 32), tb, 0, stream>>>(W1, W1T, 1024, 4096);
  tcvt_kernel<<<dim3(32, 128), tb, 0, stream>>>(W2, W2T, 4096, 1024);

  ln_kernel<<<8192, 256, 0, stream>>>(x, g1, be1, hA);
  // QKV: M=8192,N=3072,K=1024 -> 64x12 = 768 blocks (3.0 rounds)
  gemmT<128, 256, 2, 4, 0><<<dim3(64, 12), 512, 0, stream>>>(
      hA, WqkvT, qkv, nullptr, nullptr, 3072, 1024);
  vtr_kernel<<<dim3(64, 2, 64), tb, 0, stream>>>(qkv, vtg);
  attn_kernel<<<1024, 256, 0, stream>>>(qkv, vtg, attnO);
  // O-proj: N=1024 -> 64x4 = 256 blocks (1.0 round)
  gemmT<128, 256, 2, 4, 1><<<dim3(64, 4), 512, 0, stream>>>(
      attnO, WoT, x2, bo, x, 1024, 1024);
  ln_kernel<<<8192, 256, 0, stream>>>(x2, g2, be2, h2);
  // FFN1: N=4096 -> 32x16 = 512 blocks (2.0 rounds)
  gemmT<256, 256, 2, 4, 2><<<dim3(32, 16), 512, 0, stream>>>(
      h2, W1T, act, b1, nullptr, 4096, 1024);
  // FFN2: N=1024, K=4096 -> 64x4 = 256 blocks (1.0 round)
  gemmT<128, 256, 2, 4, 1><<<dim3(64, 4), 512, 0, stream>>>(
      act, W2T, (float*)d_out, b2, x2, 1024, 4096);
  (void)in_sizes; (void)n_in; (void)out_size; (void)ws_size;
}

// Round 9
// 400.513 us; speedup vs baseline: 1.3328x; 1.0361x over previous
//
#include <hip/hip_runtime.h>
#include <hip/hip_bf16.h>
#include <math.h>

// ---------------------------------------------------------------------------
// TransformerBlock on MI355X (gfx950).
// GEMMs: 2-phase counted-vmcnt schedule, st_16x32 LDS swizzle, XCD-chunked
// 4x4-supertile block mapping (L2-resident working set per XCD).
// Attn: swapped-QK^T in-register softmax, defer-max, packed b64 P-bounce.
// ---------------------------------------------------------------------------

typedef __attribute__((ext_vector_type(8))) short bf16x8;
typedef __attribute__((ext_vector_type(4))) float f32x4;

#define AS1 __attribute__((address_space(1)))
#define AS3 __attribute__((address_space(3)))

__device__ __forceinline__ void gl_lds16(const void* g, void* l) {
  __builtin_amdgcn_global_load_lds((const AS1 void*)g, (AS3 void*)l, 16, 0, 0);
}

__device__ __forceinline__ float gelu_f(float x) {
  const float c = 0.7978845608028654f;  // sqrt(2/pi)
  return 0.5f * x * (1.0f + tanhf(c * (x + 0.044715f * x * x * x)));
}

__device__ __forceinline__ float bf2f(short s) {
  unsigned u = ((unsigned)(unsigned short)s) << 16;
  return __builtin_bit_cast(float, u);
}
__device__ __forceinline__ short f2bf(float f) {
  __hip_bfloat16 h = __float2bfloat16(f);
  return __builtin_bit_cast(short, h);
}

// ---------------------------------------------------------------------------
// Weight transpose + fp32->bf16 convert:  W [K,N] fp32  ->  WT [N,K] bf16
// ---------------------------------------------------------------------------
__global__ void __launch_bounds__(256) tcvt_kernel(
    const float* __restrict__ W, __hip_bfloat16* __restrict__ WT, int K, int N) {
  __shared__ float t[32][33];
  const int n0 = blockIdx.x * 32, k0 = blockIdx.y * 32;
  const int tx = threadIdx.x, ty0 = threadIdx.y;  // 32 x 8
#pragma unroll
  for (int i = 0; i < 4; i++) {
    int ty = ty0 + i * 8;
    t[ty][tx] = W[(size_t)(k0 + ty) * N + n0 + tx];
  }
  __syncthreads();
#pragma unroll
  for (int i = 0; i < 4; i++) {
    int ty = ty0 + i * 8;
    WT[(size_t)(n0 + ty) * K + k0 + tx] = __float2bfloat16(t[tx][ty]);
  }
}

// ---------------------------------------------------------------------------
// V transpose: qkv[b*2048+s][3072] (V at col 2048+h*64+hd) -> vt[(bh*64+hd)][s]
// ---------------------------------------------------------------------------
__global__ void __launch_bounds__(256) vtr_kernel(
    const __hip_bfloat16* __restrict__ qkv, __hip_bfloat16* __restrict__ vt) {
  __shared__ __hip_bfloat16 t[32][33];
  const int s0 = blockIdx.x * 32;
  const int hd0 = blockIdx.y * 32;
  const int bh = blockIdx.z;
  const int b = bh >> 4, h = bh & 15;
  const int tx = threadIdx.x, ty0 = threadIdx.y;  // 32 x 8
  const __hip_bfloat16* src =
      qkv + (size_t)(b * 2048 + s0) * 3072 + 2048 + h * 64 + hd0;
#pragma unroll
  for (int i = 0; i < 4; i++) {
    int ty = ty0 + i * 8;
    t[ty][tx] = src[(size_t)ty * 3072 + tx];  // t[s_local][hd_local]
  }
  __syncthreads();
  __hip_bfloat16* dst = vt + ((size_t)bh * 64 + hd0) * 2048 + s0;
#pragma unroll
  for (int i = 0; i < 4; i++) {
    int ty = ty0 + i * 8;
    dst[(size_t)ty * 2048 + tx] = t[tx][ty];
  }
}

// ---------------------------------------------------------------------------
// LayerNorm over D=1024, one block (256 thr) per row, fp32 in -> bf16 out
// ---------------------------------------------------------------------------
__global__ void __launch_bounds__(256) ln_kernel(
    const float* __restrict__ x, const float* __restrict__ gma,
    const float* __restrict__ bta, __hip_bfloat16* __restrict__ out) {
  const int row = blockIdx.x;
  const int tid = threadIdx.x;
  const float4 v = ((const float4*)(x + (size_t)row * 1024))[tid];
  float s = v.x + v.y + v.z + v.w;
  float s2 = v.x * v.x + v.y * v.y + v.z * v.z + v.w * v.w;
#pragma unroll
  for (int m = 32; m; m >>= 1) {
    s += __shfl_xor(s, m);
    s2 += __shfl_xor(s2, m);
  }
  __shared__ float red[8];
  const int w = tid >> 6, lane = tid & 63;
  if (lane == 0) { red[w] = s; red[4 + w] = s2; }
  __syncthreads();
  s = red[0] + red[1] + red[2] + red[3];
  s2 = red[4] + red[5] + red[6] + red[7];
  const float mu = s * (1.0f / 1024.0f);
  const float var = s2 * (1.0f / 1024.0f) - mu * mu;
  const float rs = rsqrtf(var + 1e-5f);
  const float4 gv = ((const float4*)gma)[tid];
  const float4 bv = ((const float4*)bta)[tid];
  __hip_bfloat16* orow = out + (size_t)row * 1024 + tid * 4;
  orow[0] = __float2bfloat16((v.x - mu) * rs * gv.x + bv.x);
  orow[1] = __float2bfloat16((v.y - mu) * rs * gv.y + bv.y);
  orow[2] = __float2bfloat16((v.z - mu) * rs * gv.z + bv.z);
  orow[3] = __float2bfloat16((v.w - mu) * rs * gv.w + bv.w);
}

// ---------------------------------------------------------------------------
// GEMM template: 2-phase counted-vmcnt, st_16x32 swizzle (R6), NEW block
// mapping: XCD-contiguous chunks over a 4x4-supertile flattening so each
// XCD's working set (4 A-tiles + 4 B-tiles <= 4MB) is L2-resident.
// Requires gridDim.x%4==0, gridDim.y%4==0, nwg%16==0.
// ---------------------------------------------------------------------------
template <int BM, int BN, int WM, int WN, int EPI>
__global__ void __launch_bounds__(512, 2) gemmT(
    const __hip_bfloat16* __restrict__ Ap, const __hip_bfloat16* __restrict__ Bp,
    void* __restrict__ outp, const float* __restrict__ bias,
    const float* __restrict__ resid, int N, int K) {
  constexpr int PM = BM / WM, PN = BN / WN;   // per-wave tile
  constexpr int MR = PM / 16, NR = PN / 16;   // frags
  constexpr int UA = BM / 128, UB = BN / 128, U = UA + UB;
  constexpr int KSB = (BM + BN) * 64;         // bytes per ks region
  __shared__ __attribute__((aligned(128))) char smem[2 * 2 * KSB];
  const int tid = threadIdx.x;
  const int lane = tid & 63, w = tid >> 6;
  const int wr = w / WN, wc = w % WN;
  const int cr = lane & 15, g = lane >> 4;

  // XCD-chunked 4x4-supertile mapping
  const int gx = gridDim.x;
  const int nwg = gx * gridDim.y;
  const int orig = blockIdx.y * gx + blockIdx.x;
  const int f = (orig & 7) * (nwg >> 3) + (orig >> 3);  // XCD-contiguous flat
  const int sid = f >> 4, wit = f & 15;
  const int stm = gx >> 2;
  const int bm = (sid % stm) * 4 + (wit & 3);
  const int bn = (sid / stm) * 4 + (wit >> 2);
  const int bmr = bm * BM, bnr = bn * BN;
  const int nkt = K >> 6;

  const int srow = tid >> 2;                                   // 0..127
  const int sq = ((tid & 3) ^ (((srow >> 3) & 1) << 1)) * 8;   // elems
  const int rq = (g ^ (((cr >> 3) & 1) << 1)) * 8;             // elems

  auto stage_ks = [&](int tt, int ks) {
    char* base = smem + (tt & 1) * (2 * KSB) + ks * KSB;
#pragma unroll
    for (int ua = 0; ua < UA; ua++)
      gl_lds16(Ap + (size_t)(bmr + ua * 128 + srow) * K + tt * 64 + ks * 32 + sq,
               base + ua * 8192 + w * 1024);
#pragma unroll
    for (int ub = 0; ub < UB; ub++)
      gl_lds16(Bp + (size_t)(bnr + ub * 128 + srow) * K + tt * 64 + ks * 32 + sq,
               base + BM * 64 + ub * 8192 + w * 1024);
  };
  auto vmw = [&]() {
    if constexpr (U == 3)
      asm volatile("s_waitcnt vmcnt(9)" ::: "memory");
    else
      asm volatile("s_waitcnt vmcnt(12)" ::: "memory");
  };

  f32x4 acc[MR][NR];
#pragma unroll
  for (int i = 0; i < MR; i++)
#pragma unroll
    for (int j = 0; j < NR; j++) acc[i][j] = (f32x4){0.f, 0.f, 0.f, 0.f};

  auto compute = [&](int t, int ks) {
    const char* base = smem + (t & 1) * (2 * KSB) + ks * KSB;
    const __hip_bfloat16* pA = (const __hip_bfloat16*)base;
    const __hip_bfloat16* pB = (const __hip_bfloat16*)(base + BM * 64);
    bf16x8 av[MR], bv[NR];
#pragma unroll
    for (int m = 0; m < MR; m++)
      av[m] = *(const bf16x8*)(pA + (wr * PM + m * 16 + cr) * 32 + rq);
#pragma unroll
    for (int n = 0; n < NR; n++)
      bv[n] = *(const bf16x8*)(pB + (wc * PN + n * 16 + cr) * 32 + rq);
    __builtin_amdgcn_s_setprio(1);
#pragma unroll
    for (int m = 0; m < MR; m++)
#pragma unroll
      for (int n = 0; n < NR; n++)
        acc[m][n] =
            __builtin_amdgcn_mfma_f32_16x16x32_bf16(av[m], bv[n], acc[m][n], 0, 0, 0);
    __builtin_amdgcn_s_setprio(0);
  };

  stage_ks(0, 0);
  stage_ks(0, 1);
  stage_ks(1, 0);

  for (int t = 0; t < nkt; ++t) {
    stage_ks(t + 1 < nkt ? t + 1 : t - 1, 1);
    vmw();
    __builtin_amdgcn_s_barrier();
    compute(t, 0);
    __builtin_amdgcn_s_barrier();
    stage_ks(t + 2 < nkt ? t + 2 : t, 0);
    vmw();
    __builtin_amdgcn_s_barrier();
    compute(t, 1);
    __builtin_amdgcn_s_barrier();
  }
  asm volatile("s_waitcnt vmcnt(0)" ::: "memory");

#pragma unroll
  for (int m = 0; m < MR; m++) {
#pragma unroll
    for (int rr = 0; rr < 4; rr++) {
      const int row = bmr + wr * PM + m * 16 + g * 4 + rr;
#pragma unroll
      for (int n = 0; n < NR; n++) {
        const int col = bnr + wc * PN + n * 16 + cr;
        float v = acc[m][n][rr];
        if (EPI == 0) {
          ((__hip_bfloat16*)outp)[(size_t)row * N + col] = __float2bfloat16(v);
        } else if (EPI == 1) {
          v += bias[col] + resid[(size_t)row * N + col];
          ((float*)outp)[(size_t)row * N + col] = v;
        } else {
          v = gelu_f(v + bias[col]);
          ((__hip_bfloat16*)outp)[(size_t)row * N + col] = __float2bfloat16(v);
        }
      }
    }
  }
}

// ---------------------------------------------------------------------------
// Flash attention, causal (R8 version, unchanged). Swapped QK^T -> S^T,
// in-register softmax, defer-max (exp2 THR=8), packed b64 P-bounce,
// Q pre-scaled by 0.125*log2e, dbuf LDS staging.
// ---------------------------------------------------------------------------
__global__ void __launch_bounds__(256) attn_kernel(
    const __hip_bfloat16* __restrict__ qkv, const __hip_bfloat16* __restrict__ vt,
    __hip_bfloat16* __restrict__ o) {
  __shared__ __hip_bfloat16 sK[2][64 * 64];   // [kv][hd], slot-swizzled
  __shared__ __hip_bfloat16 sV[2][64 * 64];   // [hd][kv], slot-swizzled
  __shared__ __hip_bfloat16 pl[4][16][64];    // per-wave P^T bounce, swizzled
  const int tid = threadIdx.x, lane = tid & 63, w = tid >> 6;
  const int bid = blockIdx.x;                  // 0..1023
  const int bh = (bid & 7) + 8 * ((bid >> 3) & 7);
  const int qt = 15 - (bid >> 6);              // heavy q-tiles first
  const int b = bh >> 4, h = bh & 15;
  const int cr = lane & 15, g = lane >> 4;
  const int qr0 = qt * 128 + w * 32;           // wave's first q row
  const float NEG = -1e30f;
  const float SC2 = 0.18033688011112042f;      // 0.125 * log2(e)
  const int sw = cr & 7;                       // K/V read swizzle key
  const int sg0 = (g ^ sw) * 8;
  const int sg1 = ((g ^ sw) ^ 4) * 8;
  const int pkey = (cr & 7) << 1;              // P bounce swizzle key (even)

  // Q fragments, pre-scaled by SC2 (B-operand: col=lane&15=q, k=g*8+j)
  bf16x8 aq[2][2];
#pragma unroll
  for (int m = 0; m < 2; m++) {
    const __hip_bfloat16* qp =
        qkv + (size_t)(b * 2048 + qr0 + m * 16 + cr) * 3072 + h * 64 + g * 8;
    bf16x8 q0 = *(const bf16x8*)qp;
    bf16x8 q1 = *(const bf16x8*)(qp + 32);
#pragma unroll
    for (int j = 0; j < 8; j++) {
      aq[m][0][j] = f2bf(bf2f(q0[j]) * SC2);
      aq[m][1][j] = f2bf(bf2f(q1[j]) * SC2);
    }
  }
  const __hip_bfloat16* kbase = qkv + (size_t)(b * 2048) * 3072 + 1024 + h * 64;
  const __hip_bfloat16* vbase = vt + (size_t)bh * 64 * 2048;

  const int l8 = lane >> 3, c8 = lane & 7;
  const int c8s = (c8 ^ l8) * 8;  // pre-swizzled global source slot (elems)
#define STAGE_TILE(bi, ktile)                                                   \
  {                                                                             \
    _Pragma("unroll") for (int i = 0; i < 2; i++) {                             \
      const int rb = (i * 4 + w) * 8 + l8;                                      \
      gl_lds16(kbase + (size_t)((ktile) * 64 + rb) * 3072 + c8s,                \
               &sK[bi][(i * 4 + w) * 512]);                                     \
      gl_lds16(vbase + (size_t)rb * 2048 + (ktile) * 64 + c8s,                  \
               &sV[bi][(i * 4 + w) * 512]);                                     \
    }                                                                           \
  }

  f32x4 oacc[2][4];
#pragma unroll
  for (int m = 0; m < 2; m++)
#pragma unroll
    for (int i = 0; i < 4; i++) oacc[m][i] = (f32x4){0.f, 0.f, 0.f, 0.f};
  float mrow[2] = {NEG, NEG};   // per-lane: q = qr0 + m*16 + cr
  float lrow[2] = {0.f, 0.f};

  const int nkt = (qt + 1) * 2;
  STAGE_TILE(0, 0);
  asm volatile("s_waitcnt vmcnt(0)" ::: "memory");
  __syncthreads();
  int cur = 0;

  for (int kt = 0; kt < nkt; ++kt) {
    if (kt + 1 < nkt) STAGE_TILE(cur ^ 1, kt + 1);

    if (kt * 64 <= qr0 + 31) {
      // ---- S^T = (K Q^T): rows k (kf,g,rr), cols q (cr) ----
      f32x4 st[4][2];  // [kf][mq]
      __builtin_amdgcn_s_setprio(1);
#pragma unroll
      for (int kf = 0; kf < 4; kf++) {
        const bf16x8 bk0 = *(const bf16x8*)&sK[cur][(kf * 16 + cr) * 64 + sg0];
        const bf16x8 bk1 = *(const bf16x8*)&sK[cur][(kf * 16 + cr) * 64 + sg1];
#pragma unroll
        for (int mq = 0; mq < 2; mq++) {
          f32x4 z = (f32x4){0.f, 0.f, 0.f, 0.f};
          z = __builtin_amdgcn_mfma_f32_16x16x32_bf16(bk0, aq[mq][0], z, 0, 0, 0);
          z = __builtin_amdgcn_mfma_f32_16x16x32_bf16(bk1, aq[mq][1], z, 0, 0, 0);
          st[kf][mq] = z;
        }
      }
      __builtin_amdgcn_s_setprio(0);
      // ---- causal mask (diagonal region only) ----
      if (kt * 64 + 63 > qr0) {
#pragma unroll
        for (int kf = 0; kf < 4; kf++)
#pragma unroll
          for (int mq = 0; mq < 2; mq++)
#pragma unroll
            for (int rr = 0; rr < 4; rr++) {
              const int kvcol = kt * 64 + kf * 16 + g * 4 + rr;
              const int qrow = qr0 + mq * 16 + cr;
              if (kvcol > qrow) st[kf][mq][rr] = NEG;
            }
      }
      // ---- per mq: in-register online softmax + packed P bounce + PV ----
#pragma unroll
      for (int mq = 0; mq < 2; mq++) {
        float pmax = st[0][mq][0];
#pragma unroll
        for (int kf = 0; kf < 4; kf++)
#pragma unroll
          for (int rr = 0; rr < 4; rr++)
            pmax = fmaxf(pmax, st[kf][mq][rr]);
        pmax = fmaxf(pmax, __shfl_xor(pmax, 16));
        pmax = fmaxf(pmax, __shfl_xor(pmax, 32));
        // defer-max: rescale only when wave-wide growth exceeds THR=8 (exp2)
        if (__any(pmax > mrow[mq] + 8.0f)) {
          const float mn = fmaxf(mrow[mq], pmax);
          const float scl = exp2f(mrow[mq] - mn);
          mrow[mq] = mn;
          lrow[mq] *= scl;
          float s0 = __shfl(scl, g * 4 + 0);
          float s1 = __shfl(scl, g * 4 + 1);
          float s2 = __shfl(scl, g * 4 + 2);
          float s3 = __shfl(scl, g * 4 + 3);
#pragma unroll
          for (int nf = 0; nf < 4; nf++) {
            f32x4 t = oacc[mq][nf];
            t[0] *= s0; t[1] *= s1; t[2] *= s2; t[3] *= s3;
            oacc[mq][nf] = t;
          }
        }
        float rsum = 0.f;
#pragma unroll
        for (int kf = 0; kf < 4; kf++) {
          short4 pk;
#pragma unroll
          for (int rr = 0; rr < 4; rr++) {
            const float p = exp2f(st[kf][mq][rr] - mrow[mq]);
            rsum += p;
            ((short*)&pk)[rr] = f2bf(p);
          }
          const int slot4 = (kf * 4 + g) ^ pkey;
          *(short4*)&pl[w][cr][slot4 * 4] = pk;
        }
        rsum += __shfl_xor(rsum, 16);
        rsum += __shfl_xor(rsum, 32);
        lrow[mq] += rsum;
        // ---- PV: pa from swizzled bounce, bv from sV (unchanged layout) ----
        const bf16x8 pa0 = *(const bf16x8*)&pl[w][cr][((2 * g) ^ pkey) * 4];
        const bf16x8 pa1 = *(const bf16x8*)&pl[w][cr][((2 * g + 8) ^ pkey) * 4];
        __builtin_amdgcn_s_setprio(1);
#pragma unroll
        for (int nf = 0; nf < 4; nf++) {
          const bf16x8 bv0 = *(const bf16x8*)&sV[cur][(nf * 16 + cr) * 64 + sg0];
          const bf16x8 bv1 = *(const bf16x8*)&sV[cur][(nf * 16 + cr) * 64 + sg1];
          oacc[mq][nf] = __builtin_amdgcn_mfma_f32_16x16x32_bf16(pa0, bv0, oacc[mq][nf], 0, 0, 0);
          oacc[mq][nf] = __builtin_amdgcn_mfma_f32_16x16x32_bf16(pa1, bv1, oacc[mq][nf], 0, 0, 0);
        }
        __builtin_amdgcn_s_setprio(0);
      }
    }

    if (kt + 1 < nkt) {
      asm volatile("s_waitcnt vmcnt(0)" ::: "memory");
      __syncthreads();
      cur ^= 1;
    }
  }

  // ---- write O: gather per-row denominators from lane cr = row ----
#pragma unroll
  for (int m = 0; m < 2; m++) {
    float il[4];
#pragma unroll
    for (int rr = 0; rr < 4; rr++)
      il[rr] = 1.0f / __shfl(lrow[m], g * 4 + rr);
#pragma unroll
    for (int nf = 0; nf < 4; nf++)
#pragma unroll
      for (int rr = 0; rr < 4; rr++) {
        const int row = qr0 + m * 16 + g * 4 + rr;
        o[(size_t)(b * 2048 + row) * 1024 + h * 64 + nf * 16 + cr] =
            __float2bfloat16(oacc[m][nf][rr] * il[rr]);
      }
  }
#undef STAGE_TILE
}

// ---------------------------------------------------------------------------
// Launch
// ---------------------------------------------------------------------------
extern "C" void kernel_launch(void* const* d_in, const int* in_sizes, int n_in,
                              void* d_out, int out_size, void* d_ws, size_t ws_size,
                              hipStream_t stream) {
  const float* x   = (const float*)d_in[0];
  const float* Wq  = (const float*)d_in[1];
  const float* Wk  = (const float*)d_in[2];
  const float* Wv  = (const float*)d_in[3];
  const float* Wo  = (const float*)d_in[4];
  const float* bo  = (const float*)d_in[5];
  const float* W1  = (const float*)d_in[6];
  const float* b1  = (const float*)d_in[7];
  const float* W2  = (const float*)d_in[8];
  const float* b2  = (const float*)d_in[9];
  const float* g1  = (const float*)d_in[10];
  const float* be1 = (const float*)d_in[11];
  const float* g2  = (const float*)d_in[12];
  const float* be2 = (const float*)d_in[13];

  char* ws = (char*)d_ws;
  const size_t MB = 1024 * 1024;
  __hip_bfloat16* hA    = (__hip_bfloat16*)(ws + 0);          // 16MB (LN1 out)
  __hip_bfloat16* attnO = (__hip_bfloat16*)(ws + 0);          // 16MB (reuse)
  __hip_bfloat16* qkv   = (__hip_bfloat16*)(ws + 16 * MB);    // 48MB
  float*          x2    = (float*)(ws + 16 * MB);             // 32MB (reuse qkv)
  __hip_bfloat16* h2    = (__hip_bfloat16*)(ws + 48 * MB);    // 16MB (reuse qkv tail)
  __hip_bfloat16* vtg   = (__hip_bfloat16*)(ws + 64 * MB);    // 16MB (dead after attn)
  __hip_bfloat16* act   = (__hip_bfloat16*)(ws + 64 * MB);    // 64MB (FFN1 out)
  __hip_bfloat16* WqkvT = (__hip_bfloat16*)(ws + 128 * MB);   // 6MB  [3072,1024]
  __hip_bfloat16* WoT   = (__hip_bfloat16*)(ws + 134 * MB);   // 2MB  [1024,1024]
  __hip_bfloat16* W1T   = (__hip_bfloat16*)(ws + 136 * MB);   // 8MB  [4096,1024]
  __hip_bfloat16* W2T   = (__hip_bfloat16*)(ws + 144 * MB);   // 8MB  [1024,4096]

  const dim3 tb(32, 8);
  tcvt_kernel<<<dim3(32, 32), tb, 0, stream>>>(Wq, WqkvT, 1024, 1024);
  tcvt_kernel<<<dim3(32, 32), tb, 0, stream>>>(Wk, WqkvT + 1024 * 1024, 1024, 1024);
  tcvt_kernel<<<dim3(32, 32), tb, 0, stream>>>(Wv, WqkvT + 2 * 1024 * 1024, 1024, 1024);
  tcvt_kernel<<<dim3(32, 32), tb, 0, stream>>>(Wo, WoT, 1024, 1024);
  tcvt_kernel<<<dim3(128, 32), tb, 0, stream>>>(W1, W1T, 1024, 4096);
  tcvt_kernel<<<dim3(32, 128), tb, 0, stream>>>(W2, W2T, 4096, 1024);

  ln_kernel<<<8192, 256, 0, stream>>>(x, g1, be1, hA);
  // QKV: 64x12 = 768 blocks (3.0 rounds)
  gemmT<128, 256, 2, 4, 0><<<dim3(64, 12), 512, 0, stream>>>(
      hA, WqkvT, qkv, nullptr, nullptr, 3072, 1024);
  vtr_kernel<<<dim3(64, 2, 64), tb, 0, stream>>>(qkv, vtg);
  attn_kernel<<<1024, 256, 0, stream>>>(qkv, vtg, attnO);
  // O-proj: 64x4 = 256 blocks (1.0 round)
  gemmT<128, 256, 2, 4, 1><<<dim3(64, 4), 512, 0, stream>>>(
      attnO, WoT, x2, bo, x, 1024, 1024);
  ln_kernel<<<8192, 256, 0, stream>>>(x2, g2, be2, h2);
  // FFN1: 32x16 = 512 blocks (2.0 rounds)
  gemmT<256, 256, 2, 4, 2><<<dim3(32, 16), 512, 0, stream>>>(
      h2, W1T, act, b1, nullptr, 4096, 1024);
  // FFN2: 64x4 = 256 blocks (1.0 round)
  gemmT<128, 256, 2, 4, 1><<<dim3(64, 4), 512, 0, stream>>>(
      act, W2T, (float*)d_out, b2, x2, 1024, 4096);
  (void)in_sizes; (void)n_in; (void)out_size; (void)ws_size;
}

// Round 10
// 397.486 us; speedup vs baseline: 1.3430x; 1.0076x over previous
//
#include <hip/hip_runtime.h>
#include <hip/hip_bf16.h>
#include <math.h>

// ---------------------------------------------------------------------------
// TransformerBlock on MI355X (gfx950).
// GEMMs: 8-phase (m201-style) schedule — per K-tile NPH sub-phases of
// {ds_read subtile + issue half-tile stage -> barrier -> lgkmcnt(0) ->
//  setprio MFMA -> barrier}, ONE counted vmcnt(4) per K-tile (never drains).
// LDS [2buf][A BM x 64 | B BN x 64], slot^=(row&7) involution swizzle.
// Supertile XCD mapping (R9, FETCH-verified). Attn: swapped-QK^T softmax.
// ---------------------------------------------------------------------------

typedef __attribute__((ext_vector_type(8))) short bf16x8;
typedef __attribute__((ext_vector_type(4))) float f32x4;

#define AS1 __attribute__((address_space(1)))
#define AS3 __attribute__((address_space(3)))

__device__ __forceinline__ void gl_lds16(const void* g, void* l) {
  __builtin_amdgcn_global_load_lds((const AS1 void*)g, (AS3 void*)l, 16, 0, 0);
}

__device__ __forceinline__ float gelu_f(float x) {
  const float c = 0.7978845608028654f;  // sqrt(2/pi)
  return 0.5f * x * (1.0f + tanhf(c * (x + 0.044715f * x * x * x)));
}

__device__ __forceinline__ float bf2f(short s) {
  unsigned u = ((unsigned)(unsigned short)s) << 16;
  return __builtin_bit_cast(float, u);
}
__device__ __forceinline__ short f2bf(float f) {
  __hip_bfloat16 h = __float2bfloat16(f);
  return __builtin_bit_cast(short, h);
}

// ---------------------------------------------------------------------------
// Weight transpose + fp32->bf16 convert:  W [K,N] fp32  ->  WT [N,K] bf16
// ---------------------------------------------------------------------------
__global__ void __launch_bounds__(256) tcvt_kernel(
    const float* __restrict__ W, __hip_bfloat16* __restrict__ WT, int K, int N) {
  __shared__ float t[32][33];
  const int n0 = blockIdx.x * 32, k0 = blockIdx.y * 32;
  const int tx = threadIdx.x, ty0 = threadIdx.y;  // 32 x 8
#pragma unroll
  for (int i = 0; i < 4; i++) {
    int ty = ty0 + i * 8;
    t[ty][tx] = W[(size_t)(k0 + ty) * N + n0 + tx];
  }
  __syncthreads();
#pragma unroll
  for (int i = 0; i < 4; i++) {
    int ty = ty0 + i * 8;
    WT[(size_t)(n0 + ty) * K + k0 + tx] = __float2bfloat16(t[tx][ty]);
  }
}

// ---------------------------------------------------------------------------
// V transpose: qkv[b*2048+s][3072] (V at col 2048+h*64+hd) -> vt[(bh*64+hd)][s]
// ---------------------------------------------------------------------------
__global__ void __launch_bounds__(256) vtr_kernel(
    const __hip_bfloat16* __restrict__ qkv, __hip_bfloat16* __restrict__ vt) {
  __shared__ __hip_bfloat16 t[32][33];
  const int s0 = blockIdx.x * 32;
  const int hd0 = blockIdx.y * 32;
  const int bh = blockIdx.z;
  const int b = bh >> 4, h = bh & 15;
  const int tx = threadIdx.x, ty0 = threadIdx.y;  // 32 x 8
  const __hip_bfloat16* src =
      qkv + (size_t)(b * 2048 + s0) * 3072 + 2048 + h * 64 + hd0;
#pragma unroll
  for (int i = 0; i < 4; i++) {
    int ty = ty0 + i * 8;
    t[ty][tx] = src[(size_t)ty * 3072 + tx];  // t[s_local][hd_local]
  }
  __syncthreads();
  __hip_bfloat16* dst = vt + ((size_t)bh * 64 + hd0) * 2048 + s0;
#pragma unroll
  for (int i = 0; i < 4; i++) {
    int ty = ty0 + i * 8;
    dst[(size_t)ty * 2048 + tx] = t[tx][ty];
  }
}

// ---------------------------------------------------------------------------
// LayerNorm over D=1024, one block (256 thr) per row, fp32 in -> bf16 out
// ---------------------------------------------------------------------------
__global__ void __launch_bounds__(256) ln_kernel(
    const float* __restrict__ x, const float* __restrict__ gma,
    const float* __restrict__ bta, __hip_bfloat16* __restrict__ out) {
  const int row = blockIdx.x;
  const int tid = threadIdx.x;
  const float4 v = ((const float4*)(x + (size_t)row * 1024))[tid];
  float s = v.x + v.y + v.z + v.w;
  float s2 = v.x * v.x + v.y * v.y + v.z * v.z + v.w * v.w;
#pragma unroll
  for (int m = 32; m; m >>= 1) {
    s += __shfl_xor(s, m);
    s2 += __shfl_xor(s2, m);
  }
  __shared__ float red[8];
  const int w = tid >> 6, lane = tid & 63;
  if (lane == 0) { red[w] = s; red[4 + w] = s2; }
  __syncthreads();
  s = red[0] + red[1] + red[2] + red[3];
  s2 = red[4] + red[5] + red[6] + red[7];
  const float mu = s * (1.0f / 1024.0f);
  const float var = s2 * (1.0f / 1024.0f) - mu * mu;
  const float rs = rsqrtf(var + 1e-5f);
  const float4 gv = ((const float4*)gma)[tid];
  const float4 bv = ((const float4*)bta)[tid];
  __hip_bfloat16* orow = out + (size_t)row * 1024 + tid * 4;
  orow[0] = __float2bfloat16((v.x - mu) * rs * gv.x + bv.x);
  orow[1] = __float2bfloat16((v.y - mu) * rs * gv.y + bv.y);
  orow[2] = __float2bfloat16((v.z - mu) * rs * gv.z + bv.z);
  orow[3] = __float2bfloat16((v.w - mu) * rs * gv.w + bv.w);
}

// ---------------------------------------------------------------------------
// GEMM, 8-phase schedule. C = A[M,K] * B^T[N,K], bf16 in, fp32 acc.
// 512 thr = 8 waves (2M x 4N). Per-wave C = (BM/2) x 64. BK=64.
// Per K-tile: NPH = BM/64 phases; phase q computes acc rows [2q,2q+1] x all n
// over K=64 (16 MFMA). A-frags read per phase (4 b128); B-frags read once at
// ph0 (8 b128), held in regs. LDS: [2buf][ A: BM x 64 | B: BN x 64 ], row =
// 128B, 16B-slot swizzle slot^=(row&7) on stage-source and read (involution).
// Stage (gl_lds, 2 instr per half-tile of 128 rows): during tile t issue
// A(t+1) halves (other buf) and B(t+2) halves (curr buf; B consumed at ph0).
// Boundary: vmcnt(4) + barrier ONCE per tile — B(t+2) stays in flight (T4).
// Tail clamps restage consumed same-parity regions (idempotent).
// EPI 0: bf16 | 1: fp32 = .+bias+resid | 2: bf16 = gelu(.+bias)
// ---------------------------------------------------------------------------
template <int BM, int BN, int EPI>
__global__ void __launch_bounds__(512, 2) gemm8(
    const __hip_bfloat16* __restrict__ Ap, const __hip_bfloat16* __restrict__ Bp,
    void* __restrict__ outp, const float* __restrict__ bias,
    const float* __restrict__ resid, int N, int K) {
  constexpr int PM = BM / 2;          // per-wave M rows
  constexpr int MR = PM / 16;         // m-frags per wave
  constexpr int NPH = MR / 2;         // phases per K-tile (4 or 2)
  constexpr int HA = BM / 128;        // A half-tiles
  constexpr int ABYTES = BM * 128;
  constexpr int BBYTES = BN * 128;
  constexpr int BUFB = ABYTES + BBYTES;
  __shared__ __attribute__((aligned(128))) char smem[2 * BUFB];

  const int tid = threadIdx.x;
  const int lane = tid & 63, w = tid >> 6;
  const int wr = w >> 2, wc = w & 3;
  const int cr = lane & 15, g = lane >> 4;

  // XCD-chunked 4x4-supertile mapping (R9): gx%4==0, gy%4==0, nwg%16==0
  const int gx = gridDim.x;
  const int nwg = gx * gridDim.y;
  const int orig = blockIdx.y * gx + blockIdx.x;
  const int f = (orig & 7) * (nwg >> 3) + (orig >> 3);
  const int sid = f >> 4, wit = f & 15;
  const int stm = gx >> 2;
  const int bm = (sid % stm) * 4 + (wit & 3);
  const int bn = (sid / stm) * 4 + (wit >> 2);
  const int bmr = bm * BM, bnr = bn * BN;
  const int nkt = K >> 6;

  // staging lane geometry: wave writes 1KB chunks (8 rows x 128B); lane l ->
  // row chunk*8 + (l>>3), phys slot l&7; source logical slot = (l&7)^(l>>3)
  const int srow8 = lane >> 3;
  const int ssl = ((lane & 7) ^ srow8) * 8;  // source col offset (elems)
  const int rk = cr & 7;                     // read swizzle key

  auto stageA = [&](int tt, int h) {
    char* base = smem + (tt & 1) * BUFB + h * 16384;
#pragma unroll
    for (int c = 0; c < 2; c++) {
      const int chunk = w + c * 8;
      gl_lds16(Ap + (size_t)(bmr + h * 128 + chunk * 8 + srow8) * K + tt * 64 + ssl,
               base + chunk * 1024);
    }
  };
  auto stageB = [&](int tt, int h) {
    char* base = smem + (tt & 1) * BUFB + ABYTES + h * 16384;
#pragma unroll
    for (int c = 0; c < 2; c++) {
      const int chunk = w + c * 8;
      gl_lds16(Bp + (size_t)(bnr + h * 128 + chunk * 8 + srow8) * K + tt * 64 + ssl,
               base + chunk * 1024);
    }
  };

  f32x4 acc[MR][4];
#pragma unroll
  for (int i = 0; i < MR; i++)
#pragma unroll
    for (int j = 0; j < 4; j++) acc[i][j] = (f32x4){0.f, 0.f, 0.f, 0.f};
  bf16x8 bv[4][2];

  // Prologue: A(0), B(0), B(1); vmcnt(4) leaves B(1) in flight.
#pragma unroll
  for (int h = 0; h < HA; h++) stageA(0, h);
  stageB(0, 0); stageB(0, 1);
  stageB(1, 0); stageB(1, 1);
  asm volatile("s_waitcnt vmcnt(4)" ::: "memory");
  __builtin_amdgcn_s_barrier();

  for (int t = 0; t < nkt; ++t) {
    const char* buf = smem + (t & 1) * BUFB;
    const __hip_bfloat16* pA = (const __hip_bfloat16*)buf;
    const __hip_bfloat16* pB = (const __hip_bfloat16*)(buf + ABYTES);
    const int tnA = (t + 1 < nkt) ? t + 1 : t - 1;  // same parity as t+1
    const int tnB = (t + 2 < nkt) ? t + 2 : t;      // same parity as t
#pragma unroll
    for (int q = 0; q < NPH; q++) {
      bf16x8 av[2][2];
#pragma unroll
      for (int mm = 0; mm < 2; mm++) {
        const int row = wr * PM + (q * 2 + mm) * 16 + cr;
#pragma unroll
        for (int ks = 0; ks < 2; ks++)
          av[mm][ks] = *(const bf16x8*)(pA + row * 64 + ((ks * 4 + g) ^ rk) * 8);
      }
      if (q == 0) {
#pragma unroll
        for (int n = 0; n < 4; n++) {
          const int row = wc * 64 + n * 16 + cr;
#pragma unroll
          for (int ks = 0; ks < 2; ks++)
            bv[n][ks] = *(const bf16x8*)(pB + row * 64 + ((ks * 4 + g) ^ rk) * 8);
        }
      }
      // stage schedule: A(t+1) halves early phases, B(t+2) halves late
      if (NPH == 4) {
        if (q == 0) stageA(tnA, 0);
        else if (q == 1) stageA(tnA, 1);
        else if (q == 2) stageB(tnB, 0);
        else stageB(tnB, 1);
      } else {
        if (q == 0) stageA(tnA, 0);
        else { stageB(tnB, 0); stageB(tnB, 1); }
      }
      __builtin_amdgcn_s_barrier();
      asm volatile("s_waitcnt lgkmcnt(0)" ::: "memory");
      __builtin_amdgcn_s_setprio(1);
#pragma unroll
      for (int mm = 0; mm < 2; mm++)
#pragma unroll
        for (int n = 0; n < 4; n++)
#pragma unroll
          for (int ks = 0; ks < 2; ks++)
            acc[q * 2 + mm][n] = __builtin_amdgcn_mfma_f32_16x16x32_bf16(
                av[mm][ks], bv[n][ks], acc[q * 2 + mm][n], 0, 0, 0);
      __builtin_amdgcn_s_setprio(0);
      __builtin_amdgcn_s_barrier();
    }
    // tile boundary: A(t+1)+B(t+1) landed, B(t+2) (4 loads) stays in flight
    asm volatile("s_waitcnt vmcnt(4)" ::: "memory");
    __builtin_amdgcn_s_barrier();
  }
  asm volatile("s_waitcnt vmcnt(0)" ::: "memory");

  // Epilogue. C/D layout: col = lane&15, row = (lane>>4)*4 + reg.
#pragma unroll
  for (int m = 0; m < MR; m++) {
#pragma unroll
    for (int rr = 0; rr < 4; rr++) {
      const int row = bmr + wr * PM + m * 16 + g * 4 + rr;
#pragma unroll
      for (int n = 0; n < 4; n++) {
        const int col = bnr + wc * 64 + n * 16 + cr;
        float v = acc[m][n][rr];
        if (EPI == 0) {
          ((__hip_bfloat16*)outp)[(size_t)row * N + col] = __float2bfloat16(v);
        } else if (EPI == 1) {
          v += bias[col] + resid[(size_t)row * N + col];
          ((float*)outp)[(size_t)row * N + col] = v;
        } else {
          v = gelu_f(v + bias[col]);
          ((__hip_bfloat16*)outp)[(size_t)row * N + col] = __float2bfloat16(v);
        }
      }
    }
  }
}

// ---------------------------------------------------------------------------
// Flash attention, causal (R8 version, unchanged). Swapped QK^T -> S^T,
// in-register softmax, defer-max (exp2 THR=8), packed b64 P-bounce,
// Q pre-scaled by 0.125*log2e, dbuf LDS staging.
// ---------------------------------------------------------------------------
__global__ void __launch_bounds__(256) attn_kernel(
    const __hip_bfloat16* __restrict__ qkv, const __hip_bfloat16* __restrict__ vt,
    __hip_bfloat16* __restrict__ o) {
  __shared__ __hip_bfloat16 sK[2][64 * 64];   // [kv][hd], slot-swizzled
  __shared__ __hip_bfloat16 sV[2][64 * 64];   // [hd][kv], slot-swizzled
  __shared__ __hip_bfloat16 pl[4][16][64];    // per-wave P^T bounce, swizzled
  const int tid = threadIdx.x, lane = tid & 63, w = tid >> 6;
  const int bid = blockIdx.x;                  // 0..1023
  const int bh = (bid & 7) + 8 * ((bid >> 3) & 7);
  const int qt = 15 - (bid >> 6);              // heavy q-tiles first
  const int b = bh >> 4, h = bh & 15;
  const int cr = lane & 15, g = lane >> 4;
  const int qr0 = qt * 128 + w * 32;           // wave's first q row
  const float NEG = -1e30f;
  const float SC2 = 0.18033688011112042f;      // 0.125 * log2(e)
  const int sw = cr & 7;                       // K/V read swizzle key
  const int sg0 = (g ^ sw) * 8;
  const int sg1 = ((g ^ sw) ^ 4) * 8;
  const int pkey = (cr & 7) << 1;              // P bounce swizzle key (even)

  // Q fragments, pre-scaled by SC2 (B-operand: col=lane&15=q, k=g*8+j)
  bf16x8 aq[2][2];
#pragma unroll
  for (int m = 0; m < 2; m++) {
    const __hip_bfloat16* qp =
        qkv + (size_t)(b * 2048 + qr0 + m * 16 + cr) * 3072 + h * 64 + g * 8;
    bf16x8 q0 = *(const bf16x8*)qp;
    bf16x8 q1 = *(const bf16x8*)(qp + 32);
#pragma unroll
    for (int j = 0; j < 8; j++) {
      aq[m][0][j] = f2bf(bf2f(q0[j]) * SC2);
      aq[m][1][j] = f2bf(bf2f(q1[j]) * SC2);
    }
  }
  const __hip_bfloat16* kbase = qkv + (size_t)(b * 2048) * 3072 + 1024 + h * 64;
  const __hip_bfloat16* vbase = vt + (size_t)bh * 64 * 2048;

  const int l8 = lane >> 3, c8 = lane & 7;
  const int c8s = (c8 ^ l8) * 8;  // pre-swizzled global source slot (elems)
#define STAGE_TILE(bi, ktile)                                                   \
  {                                                                             \
    _Pragma("unroll") for (int i = 0; i < 2; i++) {                             \
      const int rb = (i * 4 + w) * 8 + l8;                                      \
      gl_lds16(kbase + (size_t)((ktile) * 64 + rb) * 3072 + c8s,                \
               &sK[bi][(i * 4 + w) * 512]);                                     \
      gl_lds16(vbase + (size_t)rb * 2048 + (ktile) * 64 + c8s,                  \
               &sV[bi][(i * 4 + w) * 512]);                                     \
    }                                                                           \
  }

  f32x4 oacc[2][4];
#pragma unroll
  for (int m = 0; m < 2; m++)
#pragma unroll
    for (int i = 0; i < 4; i++) oacc[m][i] = (f32x4){0.f, 0.f, 0.f, 0.f};
  float mrow[2] = {NEG, NEG};   // per-lane: q = qr0 + m*16 + cr
  float lrow[2] = {0.f, 0.f};

  const int nkt = (qt + 1) * 2;
  STAGE_TILE(0, 0);
  asm volatile("s_waitcnt vmcnt(0)" ::: "memory");
  __syncthreads();
  int cur = 0;

  for (int kt = 0; kt < nkt; ++kt) {
    if (kt + 1 < nkt) STAGE_TILE(cur ^ 1, kt + 1);

    if (kt * 64 <= qr0 + 31) {
      // ---- S^T = (K Q^T): rows k (kf,g,rr), cols q (cr) ----
      f32x4 st[4][2];  // [kf][mq]
      __builtin_amdgcn_s_setprio(1);
#pragma unroll
      for (int kf = 0; kf < 4; kf++) {
        const bf16x8 bk0 = *(const bf16x8*)&sK[cur][(kf * 16 + cr) * 64 + sg0];
        const bf16x8 bk1 = *(const bf16x8*)&sK[cur][(kf * 16 + cr) * 64 + sg1];
#pragma unroll
        for (int mq = 0; mq < 2; mq++) {
          f32x4 z = (f32x4){0.f, 0.f, 0.f, 0.f};
          z = __builtin_amdgcn_mfma_f32_16x16x32_bf16(bk0, aq[mq][0], z, 0, 0, 0);
          z = __builtin_amdgcn_mfma_f32_16x16x32_bf16(bk1, aq[mq][1], z, 0, 0, 0);
          st[kf][mq] = z;
        }
      }
      __builtin_amdgcn_s_setprio(0);
      // ---- causal mask (diagonal region only) ----
      if (kt * 64 + 63 > qr0) {
#pragma unroll
        for (int kf = 0; kf < 4; kf++)
#pragma unroll
          for (int mq = 0; mq < 2; mq++)
#pragma unroll
            for (int rr = 0; rr < 4; rr++) {
              const int kvcol = kt * 64 + kf * 16 + g * 4 + rr;
              const int qrow = qr0 + mq * 16 + cr;
              if (kvcol > qrow) st[kf][mq][rr] = NEG;
            }
      }
      // ---- per mq: in-register online softmax + packed P bounce + PV ----
#pragma unroll
      for (int mq = 0; mq < 2; mq++) {
        float pmax = st[0][mq][0];
#pragma unroll
        for (int kf = 0; kf < 4; kf++)
#pragma unroll
          for (int rr = 0; rr < 4; rr++)
            pmax = fmaxf(pmax, st[kf][mq][rr]);
        pmax = fmaxf(pmax, __shfl_xor(pmax, 16));
        pmax = fmaxf(pmax, __shfl_xor(pmax, 32));
        // defer-max: rescale only when wave-wide growth exceeds THR=8 (exp2)
        if (__any(pmax > mrow[mq] + 8.0f)) {
          const float mn = fmaxf(mrow[mq], pmax);
          const float scl = exp2f(mrow[mq] - mn);
          mrow[mq] = mn;
          lrow[mq] *= scl;
          float s0 = __shfl(scl, g * 4 + 0);
          float s1 = __shfl(scl, g * 4 + 1);
          float s2 = __shfl(scl, g * 4 + 2);
          float s3 = __shfl(scl, g * 4 + 3);
#pragma unroll
          for (int nf = 0; nf < 4; nf++) {
            f32x4 t = oacc[mq][nf];
            t[0] *= s0; t[1] *= s1; t[2] *= s2; t[3] *= s3;
            oacc[mq][nf] = t;
          }
        }
        float rsum = 0.f;
#pragma unroll
        for (int kf = 0; kf < 4; kf++) {
          short4 pk;
#pragma unroll
          for (int rr = 0; rr < 4; rr++) {
            const float p = exp2f(st[kf][mq][rr] - mrow[mq]);
            rsum += p;
            ((short*)&pk)[rr] = f2bf(p);
          }
          const int slot4 = (kf * 4 + g) ^ pkey;
          *(short4*)&pl[w][cr][slot4 * 4] = pk;
        }
        rsum += __shfl_xor(rsum, 16);
        rsum += __shfl_xor(rsum, 32);
        lrow[mq] += rsum;
        // ---- PV: pa from swizzled bounce, bv from sV (unchanged layout) ----
        const bf16x8 pa0 = *(const bf16x8*)&pl[w][cr][((2 * g) ^ pkey) * 4];
        const bf16x8 pa1 = *(const bf16x8*)&pl[w][cr][((2 * g + 8) ^ pkey) * 4];
        __builtin_amdgcn_s_setprio(1);
#pragma unroll
        for (int nf = 0; nf < 4; nf++) {
          const bf16x8 bv0 = *(const bf16x8*)&sV[cur][(nf * 16 + cr) * 64 + sg0];
          const bf16x8 bv1 = *(const bf16x8*)&sV[cur][(nf * 16 + cr) * 64 + sg1];
          oacc[mq][nf] = __builtin_amdgcn_mfma_f32_16x16x32_bf16(pa0, bv0, oacc[mq][nf], 0, 0, 0);
          oacc[mq][nf] = __builtin_amdgcn_mfma_f32_16x16x32_bf16(pa1, bv1, oacc[mq][nf], 0, 0, 0);
        }
        __builtin_amdgcn_s_setprio(0);
      }
    }

    if (kt + 1 < nkt) {
      asm volatile("s_waitcnt vmcnt(0)" ::: "memory");
      __syncthreads();
      cur ^= 1;
    }
  }

  // ---- write O: gather per-row denominators from lane cr = row ----
#pragma unroll
  for (int m = 0; m < 2; m++) {
    float il[4];
#pragma unroll
    for (int rr = 0; rr < 4; rr++)
      il[rr] = 1.0f / __shfl(lrow[m], g * 4 + rr);
#pragma unroll
    for (int nf = 0; nf < 4; nf++)
#pragma unroll
      for (int rr = 0; rr < 4; rr++) {
        const int row = qr0 + m * 16 + g * 4 + rr;
        o[(size_t)(b * 2048 + row) * 1024 + h * 64 + nf * 16 + cr] =
            __float2bfloat16(oacc[m][nf][rr] * il[rr]);
      }
  }
#undef STAGE_TILE
}

// ---------------------------------------------------------------------------
// Launch
// ---------------------------------------------------------------------------
extern "C" void kernel_launch(void* const* d_in, const int* in_sizes, int n_in,
                              void* d_out, int out_size, void* d_ws, size_t ws_size,
                              hipStream_t stream) {
  const float* x   = (const float*)d_in[0];
  const float* Wq  = (const float*)d_in[1];
  const float* Wk  = (const float*)d_in[2];
  const float* Wv  = (const float*)d_in[3];
  const float* Wo  = (const float*)d_in[4];
  const float* bo  = (const float*)d_in[5];
  const float* W1  = (const float*)d_in[6];
  const float* b1  = (const float*)d_in[7];
  const float* W2  = (const float*)d_in[8];
  const float* b2  = (const float*)d_in[9];
  const float* g1  = (const float*)d_in[10];
  const float* be1 = (const float*)d_in[11];
  const float* g2  = (const float*)d_in[12];
  const float* be2 = (const float*)d_in[13];

  char* ws = (char*)d_ws;
  const size_t MB = 1024 * 1024;
  __hip_bfloat16* hA    = (__hip_bfloat16*)(ws + 0);          // 16MB (LN1 out)
  __hip_bfloat16* attnO = (__hip_bfloat16*)(ws + 0);          // 16MB (reuse)
  __hip_bfloat16* qkv   = (__hip_bfloat16*)(ws + 16 * MB);    // 48MB
  float*          x2    = (float*)(ws + 16 * MB);             // 32MB (reuse qkv)
  __hip_bfloat16* h2    = (__hip_bfloat16*)(ws + 48 * MB);    // 16MB (reuse qkv tail)
  __hip_bfloat16* vtg   = (__hip_bfloat16*)(ws + 64 * MB);    // 16MB (dead after attn)
  __hip_bfloat16* act   = (__hip_bfloat16*)(ws + 64 * MB);    // 64MB (FFN1 out)
  __hip_bfloat16* WqkvT = (__hip_bfloat16*)(ws + 128 * MB);   // 6MB  [3072,1024]
  __hip_bfloat16* WoT   = (__hip_bfloat16*)(ws + 134 * MB);   // 2MB  [1024,1024]
  __hip_bfloat16* W1T   = (__hip_bfloat16*)(ws + 136 * MB);   // 8MB  [4096,1024]
  __hip_bfloat16* W2T   = (__hip_bfloat16*)(ws + 144 * MB);   // 8MB  [1024,4096]

  const dim3 tb(32, 8);
  tcvt_kernel<<<dim3(32, 32), tb, 0, stream>>>(Wq, WqkvT, 1024, 1024);
  tcvt_kernel<<<dim3(32, 32), tb, 0, stream>>>(Wk, WqkvT + 1024 * 1024, 1024, 1024);
  tcvt_kernel<<<dim3(32, 32), tb, 0, stream>>>(Wv, WqkvT + 2 * 1024 * 1024, 1024, 1024);
  tcvt_kernel<<<dim3(32, 32), tb, 0, stream>>>(Wo, WoT, 1024, 1024);
  tcvt_kernel<<<dim3(128, 32), tb, 0, stream>>>(W1, W1T, 1024, 4096);
  tcvt_kernel<<<dim3(32, 128), tb, 0, stream>>>(W2, W2T, 4096, 1024);

  ln_kernel<<<8192, 256, 0, stream>>>(x, g1, be1, hA);
  // QKV: 64x12 = 768 blocks (3.0 rounds), NPH=2
  gemm8<128, 256, 0><<<dim3(64, 12), 512, 0, stream>>>(
      hA, WqkvT, qkv, nullptr, nullptr, 3072, 1024);
  vtr_kernel<<<dim3(64, 2, 64), tb, 0, stream>>>(qkv, vtg);
  attn_kernel<<<1024, 256, 0, stream>>>(qkv, vtg, attnO);
  // O-proj: 64x4 = 256 blocks (1.0 round), NPH=2
  gemm8<128, 256, 1><<<dim3(64, 4), 512, 0, stream>>>(
      attnO, WoT, x2, bo, x, 1024, 1024);
  ln_kernel<<<8192, 256, 0, stream>>>(x2, g2, be2, h2);
  // FFN1: 32x16 = 512 blocks (2.0 rounds), NPH=4 (m201-verified shape)
  gemm8<256, 256, 2><<<dim3(32, 16), 512, 0, stream>>>(
      h2, W1T, act, b1, nullptr, 4096, 1024);
  // FFN2: 64x4 = 256 blocks (1.0 round), K=4096, NPH=2
  gemm8<128, 256, 1><<<dim3(64, 4), 512, 0, stream>>>(
      act, W2T, (float*)d_out, b2, x2, 1024, 4096);
  (void)in_sizes; (void)n_in; (void)out_size; (void)ws_size;
}

// Round 11
// 387.589 us; speedup vs baseline: 1.3772x; 1.0255x over previous
//
#include <hip/hip_runtime.h>
#include <hip/hip_bf16.h>
#include <math.h>

// ---------------------------------------------------------------------------
// TransformerBlock on MI355X (gfx950).
// GEMMs: m201-style 8-phase schedule with CLEAN ADDRESSING: 2x-unrolled
// K-loop (compile-time buffer), precomputed LDS read pointers (ds_read via
// offset immediates), 32-bit precomputed global staging offsets, counted
// vmcnt(4) folded into last phase. Supertile XCD mapping (R9).
// Attn: swapped-QK^T in-register softmax (R8).
// ---------------------------------------------------------------------------

typedef __attribute__((ext_vector_type(8))) short bf16x8;
typedef __attribute__((ext_vector_type(4))) float f32x4;

#define AS1 __attribute__((address_space(1)))
#define AS3 __attribute__((address_space(3)))

__device__ __forceinline__ void gl_lds16(const void* g, void* l) {
  __builtin_amdgcn_global_load_lds((const AS1 void*)g, (AS3 void*)l, 16, 0, 0);
}

__device__ __forceinline__ float gelu_f(float x) {
  const float c = 0.7978845608028654f;  // sqrt(2/pi)
  return 0.5f * x * (1.0f + tanhf(c * (x + 0.044715f * x * x * x)));
}

__device__ __forceinline__ float bf2f(short s) {
  unsigned u = ((unsigned)(unsigned short)s) << 16;
  return __builtin_bit_cast(float, u);
}
__device__ __forceinline__ short f2bf(float f) {
  __hip_bfloat16 h = __float2bfloat16(f);
  return __builtin_bit_cast(short, h);
}

// ---------------------------------------------------------------------------
// Weight transpose + fp32->bf16 convert:  W [K,N] fp32  ->  WT [N,K] bf16
// ---------------------------------------------------------------------------
__global__ void __launch_bounds__(256) tcvt_kernel(
    const float* __restrict__ W, __hip_bfloat16* __restrict__ WT, int K, int N) {
  __shared__ float t[32][33];
  const int n0 = blockIdx.x * 32, k0 = blockIdx.y * 32;
  const int tx = threadIdx.x, ty0 = threadIdx.y;  // 32 x 8
#pragma unroll
  for (int i = 0; i < 4; i++) {
    int ty = ty0 + i * 8;
    t[ty][tx] = W[(size_t)(k0 + ty) * N + n0 + tx];
  }
  __syncthreads();
#pragma unroll
  for (int i = 0; i < 4; i++) {
    int ty = ty0 + i * 8;
    WT[(size_t)(n0 + ty) * K + k0 + tx] = __float2bfloat16(t[tx][ty]);
  }
}

// ---------------------------------------------------------------------------
// V transpose: qkv[b*2048+s][3072] (V at col 2048+h*64+hd) -> vt[(bh*64+hd)][s]
// ---------------------------------------------------------------------------
__global__ void __launch_bounds__(256) vtr_kernel(
    const __hip_bfloat16* __restrict__ qkv, __hip_bfloat16* __restrict__ vt) {
  __shared__ __hip_bfloat16 t[32][33];
  const int s0 = blockIdx.x * 32;
  const int hd0 = blockIdx.y * 32;
  const int bh = blockIdx.z;
  const int b = bh >> 4, h = bh & 15;
  const int tx = threadIdx.x, ty0 = threadIdx.y;  // 32 x 8
  const __hip_bfloat16* src =
      qkv + (size_t)(b * 2048 + s0) * 3072 + 2048 + h * 64 + hd0;
#pragma unroll
  for (int i = 0; i < 4; i++) {
    int ty = ty0 + i * 8;
    t[ty][tx] = src[(size_t)ty * 3072 + tx];  // t[s_local][hd_local]
  }
  __syncthreads();
  __hip_bfloat16* dst = vt + ((size_t)bh * 64 + hd0) * 2048 + s0;
#pragma unroll
  for (int i = 0; i < 4; i++) {
    int ty = ty0 + i * 8;
    dst[(size_t)ty * 2048 + tx] = t[tx][ty];
  }
}

// ---------------------------------------------------------------------------
// LayerNorm over D=1024, one block (256 thr) per row, fp32 in -> bf16 out
// ---------------------------------------------------------------------------
__global__ void __launch_bounds__(256) ln_kernel(
    const float* __restrict__ x, const float* __restrict__ gma,
    const float* __restrict__ bta, __hip_bfloat16* __restrict__ out) {
  const int row = blockIdx.x;
  const int tid = threadIdx.x;
  const float4 v = ((const float4*)(x + (size_t)row * 1024))[tid];
  float s = v.x + v.y + v.z + v.w;
  float s2 = v.x * v.x + v.y * v.y + v.z * v.z + v.w * v.w;
#pragma unroll
  for (int m = 32; m; m >>= 1) {
    s += __shfl_xor(s, m);
    s2 += __shfl_xor(s2, m);
  }
  __shared__ float red[8];
  const int w = tid >> 6, lane = tid & 63;
  if (lane == 0) { red[w] = s; red[4 + w] = s2; }
  __syncthreads();
  s = red[0] + red[1] + red[2] + red[3];
  s2 = red[4] + red[5] + red[6] + red[7];
  const float mu = s * (1.0f / 1024.0f);
  const float var = s2 * (1.0f / 1024.0f) - mu * mu;
  const float rs = rsqrtf(var + 1e-5f);
  const float4 gv = ((const float4*)gma)[tid];
  const float4 bv = ((const float4*)bta)[tid];
  __hip_bfloat16* orow = out + (size_t)row * 1024 + tid * 4;
  orow[0] = __float2bfloat16((v.x - mu) * rs * gv.x + bv.x);
  orow[1] = __float2bfloat16((v.y - mu) * rs * gv.y + bv.y);
  orow[2] = __float2bfloat16((v.z - mu) * rs * gv.z + bv.z);
  orow[3] = __float2bfloat16((v.w - mu) * rs * gv.w + bv.w);
}

// ---------------------------------------------------------------------------
// GEMM, 8-phase schedule, clean addressing. C = A[M,K]*B^T[N,K], bf16/fp32.
// 512 thr = 8 waves (2M x 4N); per-wave C = (BM/2) x 64; BK=64.
// Per K-tile NPH phases: {4x ds_read_b128 A (+8x B at q0, B held in regs),
// stage 1 unit (2 gl_lds) -> barrier -> lgkmcnt(0) -> setprio 16 MFMA ->
// [last phase: vmcnt(4)] -> barrier}. B(t+2) staged into current buffer
// (B consumed at q0), A(t+1) into other buffer; boundary vmcnt(4) keeps
// B(t+2) in flight (T4). 2x-unrolled K-loop => all buffer indices compile-
// time; LDS reads via precomputed pointers + offset immediates; staging via
// precomputed 32-bit offsets + t*128. slot^=(row&7) involution swizzle.
// EPI 0: bf16 | 1: fp32 = .+bias+resid | 2: bf16 = gelu(.+bias)
// ---------------------------------------------------------------------------
template <int BM, int BN, int EPI>
__global__ void __launch_bounds__(512, 2) gemm8(
    const __hip_bfloat16* __restrict__ Ap, const __hip_bfloat16* __restrict__ Bp,
    void* __restrict__ outp, const float* __restrict__ bias,
    const float* __restrict__ resid, int N, int K) {
  constexpr int PM = BM / 2;          // per-wave M rows
  constexpr int MR = PM / 16;         // m-frags per wave
  constexpr int NPH = MR / 2;         // phases per K-tile (4 or 2)
  constexpr int HA = BM / 128;        // A half-tiles
  constexpr int ABYTES = BM * 128;
  constexpr int BUFB = ABYTES + BN * 128;
  __shared__ __attribute__((aligned(128))) char smem[2 * BUFB];

  const int tid = threadIdx.x;
  const int lane = tid & 63, w = tid >> 6;
  const int wr = w >> 2, wc = w & 3;
  const int cr = lane & 15, g = lane >> 4;

  // XCD-chunked 4x4-supertile mapping (R9; FETCH-verified 2.7x reduction)
  const int gx = gridDim.x;
  const int nwg = gx * gridDim.y;
  const int orig = blockIdx.y * gx + blockIdx.x;
  const int f = (orig & 7) * (nwg >> 3) + (orig >> 3);
  const int sid = f >> 4, wit = f & 15;
  const int stm = gx >> 2;
  const int bm = (sid % stm) * 4 + (wit & 3);
  const int bn = (sid / stm) * 4 + (wit >> 2);
  const int bmr = bm * BM, bnr = bn * BN;
  const int nkt = K >> 6;

  // ---- precomputed staging offsets (32-bit; max 64MB fits) ----
  const int srow8 = lane >> 3;
  const int ssl = ((lane & 7) ^ srow8) * 8;  // swizzled source slot (elems)
  unsigned aofs[2][2], bofs[2][2];           // [half][chunk-pair]
#pragma unroll
  for (int h = 0; h < 2; h++)
#pragma unroll
    for (int c = 0; c < 2; c++) {
      const int ha = (h < HA) ? h : 0;
      aofs[h][c] =
          (unsigned)(((bmr + ha * 128 + (w + c * 8) * 8 + srow8) * K + ssl) * 2);
      bofs[h][c] =
          (unsigned)(((bnr + h * 128 + (w + c * 8) * 8 + srow8) * K + ssl) * 2);
    }

  // ---- precomputed LDS read pointers (all reads = ptr + imm) ----
  const int rk = cr & 7;
  const char* aP[2][2];  // [buf][ks]
  const char* bP[2][2];
#pragma unroll
  for (int bf = 0; bf < 2; bf++)
#pragma unroll
    for (int ks = 0; ks < 2; ks++) {
      aP[bf][ks] =
          smem + bf * BUFB + (wr * PM + cr) * 128 + ((ks * 4 + g) ^ rk) * 16;
      bP[bf][ks] = smem + bf * BUFB + ABYTES + (wc * 64 + cr) * 128 +
                   ((ks * 4 + g) ^ rk) * 16;
    }

#define STG_A(BUF, tt, h)                                                     \
  do {                                                                        \
    const unsigned col = (unsigned)(tt) * 128u;                               \
    gl_lds16((const char*)Ap + aofs[h][0] + col,                              \
             smem + (BUF) * BUFB + (h) * 16384 + w * 1024);                   \
    gl_lds16((const char*)Ap + aofs[h][1] + col,                              \
             smem + (BUF) * BUFB + (h) * 16384 + (w + 8) * 1024);             \
  } while (0)
#define STG_B(BUF, tt, h)                                                     \
  do {                                                                        \
    const unsigned col = (unsigned)(tt) * 128u;                               \
    gl_lds16((const char*)Bp + bofs[h][0] + col,                              \
             smem + (BUF) * BUFB + ABYTES + (h) * 16384 + w * 1024);          \
    gl_lds16((const char*)Bp + bofs[h][1] + col,                              \
             smem + (BUF) * BUFB + ABYTES + (h) * 16384 + (w + 8) * 1024);    \
  } while (0)

  f32x4 acc[MR][4];
#pragma unroll
  for (int i = 0; i < MR; i++)
#pragma unroll
    for (int j = 0; j < 4; j++) acc[i][j] = (f32x4){0.f, 0.f, 0.f, 0.f};
  bf16x8 bv[4][2];

  // Prologue: A(0), B(0), B(1); vmcnt(4) leaves B(1) in flight.
#pragma unroll
  for (int h = 0; h < HA; h++) STG_A(0, 0, h);
  STG_B(0, 0, 0); STG_B(0, 0, 1);
  STG_B(1, 1, 0); STG_B(1, 1, 1);
  asm volatile("s_waitcnt vmcnt(4)" ::: "memory");
  __builtin_amdgcn_s_barrier();

#define TILE_BODY(BUF, t)                                                     \
  {                                                                           \
    const int tA = ((t) + 1 < nkt) ? (t) + 1 : (t) - 1;                       \
    const int tB = ((t) + 2 < nkt) ? (t) + 2 : (t);                           \
    _Pragma("unroll") for (int q = 0; q < NPH; q++) {                         \
      bf16x8 av[2][2];                                                        \
      _Pragma("unroll") for (int mm = 0; mm < 2; mm++)                        \
          _Pragma("unroll") for (int ks = 0; ks < 2; ks++) av[mm][ks] =       \
          *(const bf16x8*)(aP[BUF][ks] + (q * 2 + mm) * 2048);                \
      if (q == 0) {                                                           \
        _Pragma("unroll") for (int n = 0; n < 4; n++)                         \
            _Pragma("unroll") for (int ks = 0; ks < 2; ks++) bv[n][ks] =      \
            *(const bf16x8*)(bP[BUF][ks] + n * 2048);                         \
      }                                                                       \
      if constexpr (NPH == 4) {                                               \
        if (q == 0) { STG_A((BUF) ^ 1, tA, 0); }                              \
        else if (q == 1) { STG_A((BUF) ^ 1, tA, 1); }                         \
        else if (q == 2) { STG_B(BUF, tB, 0); }                               \
        else { STG_B(BUF, tB, 1); }                                           \
      } else {                                                                \
        if (q == 0) { STG_A((BUF) ^ 1, tA, 0); }                              \
        else { STG_B(BUF, tB, 0); STG_B(BUF, tB, 1); }                        \
      }                                                                       \
      __builtin_amdgcn_s_barrier();                                           \
      asm volatile("s_waitcnt lgkmcnt(0)" ::: "memory");                      \
      __builtin_amdgcn_s_setprio(1);                                          \
      _Pragma("unroll") for (int mm = 0; mm < 2; mm++)                        \
          _Pragma("unroll") for (int n = 0; n < 4; n++)                       \
              _Pragma("unroll") for (int ks = 0; ks < 2; ks++)                \
                  acc[q * 2 + mm][n] =                                        \
          __builtin_amdgcn_mfma_f32_16x16x32_bf16(av[mm][ks], bv[n][ks],      \
                                                  acc[q * 2 + mm][n], 0, 0, 0); \
      __builtin_amdgcn_s_setprio(0);                                          \
      if (q == NPH - 1)                                                       \
        asm volatile("s_waitcnt vmcnt(4)" ::: "memory");                      \
      __builtin_amdgcn_s_barrier();                                           \
    }                                                                         \
  }

  for (int t = 0; t < nkt; t += 2) {
    TILE_BODY(0, t)
    TILE_BODY(1, t + 1)
  }
  asm volatile("s_waitcnt vmcnt(0)" ::: "memory");

  // Epilogue. C/D layout: col = lane&15, row = (lane>>4)*4 + reg.
#pragma unroll
  for (int m = 0; m < MR; m++) {
#pragma unroll
    for (int rr = 0; rr < 4; rr++) {
      const int row = bmr + wr * PM + m * 16 + g * 4 + rr;
#pragma unroll
      for (int n = 0; n < 4; n++) {
        const int col = bnr + wc * 64 + n * 16 + cr;
        float v = acc[m][n][rr];
        if (EPI == 0) {
          ((__hip_bfloat16*)outp)[(size_t)row * N + col] = __float2bfloat16(v);
        } else if (EPI == 1) {
          v += bias[col] + resid[(size_t)row * N + col];
          ((float*)outp)[(size_t)row * N + col] = v;
        } else {
          v = gelu_f(v + bias[col]);
          ((__hip_bfloat16*)outp)[(size_t)row * N + col] = __float2bfloat16(v);
        }
      }
    }
  }
#undef STG_A
#undef STG_B
#undef TILE_BODY
}

// ---------------------------------------------------------------------------
// Flash attention, causal (R8 version, unchanged). Swapped QK^T -> S^T,
// in-register softmax, defer-max (exp2 THR=8), packed b64 P-bounce,
// Q pre-scaled by 0.125*log2e, dbuf LDS staging.
// ---------------------------------------------------------------------------
__global__ void __launch_bounds__(256) attn_kernel(
    const __hip_bfloat16* __restrict__ qkv, const __hip_bfloat16* __restrict__ vt,
    __hip_bfloat16* __restrict__ o) {
  __shared__ __hip_bfloat16 sK[2][64 * 64];   // [kv][hd], slot-swizzled
  __shared__ __hip_bfloat16 sV[2][64 * 64];   // [hd][kv], slot-swizzled
  __shared__ __hip_bfloat16 pl[4][16][64];    // per-wave P^T bounce, swizzled
  const int tid = threadIdx.x, lane = tid & 63, w = tid >> 6;
  const int bid = blockIdx.x;                  // 0..1023
  const int bh = (bid & 7) + 8 * ((bid >> 3) & 7);
  const int qt = 15 - (bid >> 6);              // heavy q-tiles first
  const int b = bh >> 4, h = bh & 15;
  const int cr = lane & 15, g = lane >> 4;
  const int qr0 = qt * 128 + w * 32;           // wave's first q row
  const float NEG = -1e30f;
  const float SC2 = 0.18033688011112042f;      // 0.125 * log2(e)
  const int sw = cr & 7;                       // K/V read swizzle key
  const int sg0 = (g ^ sw) * 8;
  const int sg1 = ((g ^ sw) ^ 4) * 8;
  const int pkey = (cr & 7) << 1;              // P bounce swizzle key (even)

  // Q fragments, pre-scaled by SC2 (B-operand: col=lane&15=q, k=g*8+j)
  bf16x8 aq[2][2];
#pragma unroll
  for (int m = 0; m < 2; m++) {
    const __hip_bfloat16* qp =
        qkv + (size_t)(b * 2048 + qr0 + m * 16 + cr) * 3072 + h * 64 + g * 8;
    bf16x8 q0 = *(const bf16x8*)qp;
    bf16x8 q1 = *(const bf16x8*)(qp + 32);
#pragma unroll
    for (int j = 0; j < 8; j++) {
      aq[m][0][j] = f2bf(bf2f(q0[j]) * SC2);
      aq[m][1][j] = f2bf(bf2f(q1[j]) * SC2);
    }
  }
  const __hip_bfloat16* kbase = qkv + (size_t)(b * 2048) * 3072 + 1024 + h * 64;
  const __hip_bfloat16* vbase = vt + (size_t)bh * 64 * 2048;

  const int l8 = lane >> 3, c8 = lane & 7;
  const int c8s = (c8 ^ l8) * 8;  // pre-swizzled global source slot (elems)
#define STAGE_TILE(bi, ktile)                                                   \
  {                                                                             \
    _Pragma("unroll") for (int i = 0; i < 2; i++) {                             \
      const int rb = (i * 4 + w) * 8 + l8;                                      \
      gl_lds16(kbase + (size_t)((ktile) * 64 + rb) * 3072 + c8s,                \
               &sK[bi][(i * 4 + w) * 512]);                                     \
      gl_lds16(vbase + (size_t)rb * 2048 + (ktile) * 64 + c8s,                  \
               &sV[bi][(i * 4 + w) * 512]);                                     \
    }                                                                           \
  }

  f32x4 oacc[2][4];
#pragma unroll
  for (int m = 0; m < 2; m++)
#pragma unroll
    for (int i = 0; i < 4; i++) oacc[m][i] = (f32x4){0.f, 0.f, 0.f, 0.f};
  float mrow[2] = {NEG, NEG};   // per-lane: q = qr0 + m*16 + cr
  float lrow[2] = {0.f, 0.f};

  const int nkt = (qt + 1) * 2;
  STAGE_TILE(0, 0);
  asm volatile("s_waitcnt vmcnt(0)" ::: "memory");
  __syncthreads();
  int cur = 0;

  for (int kt = 0; kt < nkt; ++kt) {
    if (kt + 1 < nkt) STAGE_TILE(cur ^ 1, kt + 1);

    if (kt * 64 <= qr0 + 31) {
      // ---- S^T = (K Q^T): rows k (kf,g,rr), cols q (cr) ----
      f32x4 st[4][2];  // [kf][mq]
      __builtin_amdgcn_s_setprio(1);
#pragma unroll
      for (int kf = 0; kf < 4; kf++) {
        const bf16x8 bk0 = *(const bf16x8*)&sK[cur][(kf * 16 + cr) * 64 + sg0];
        const bf16x8 bk1 = *(const bf16x8*)&sK[cur][(kf * 16 + cr) * 64 + sg1];
#pragma unroll
        for (int mq = 0; mq < 2; mq++) {
          f32x4 z = (f32x4){0.f, 0.f, 0.f, 0.f};
          z = __builtin_amdgcn_mfma_f32_16x16x32_bf16(bk0, aq[mq][0], z, 0, 0, 0);
          z = __builtin_amdgcn_mfma_f32_16x16x32_bf16(bk1, aq[mq][1], z, 0, 0, 0);
          st[kf][mq] = z;
        }
      }
      __builtin_amdgcn_s_setprio(0);
      // ---- causal mask (diagonal region only) ----
      if (kt * 64 + 63 > qr0) {
#pragma unroll
        for (int kf = 0; kf < 4; kf++)
#pragma unroll
          for (int mq = 0; mq < 2; mq++)
#pragma unroll
            for (int rr = 0; rr < 4; rr++) {
              const int kvcol = kt * 64 + kf * 16 + g * 4 + rr;
              const int qrow = qr0 + mq * 16 + cr;
              if (kvcol > qrow) st[kf][mq][rr] = NEG;
            }
      }
      // ---- per mq: in-register online softmax + packed P bounce + PV ----
#pragma unroll
      for (int mq = 0; mq < 2; mq++) {
        float pmax = st[0][mq][0];
#pragma unroll
        for (int kf = 0; kf < 4; kf++)
#pragma unroll
          for (int rr = 0; rr < 4; rr++)
            pmax = fmaxf(pmax, st[kf][mq][rr]);
        pmax = fmaxf(pmax, __shfl_xor(pmax, 16));
        pmax = fmaxf(pmax, __shfl_xor(pmax, 32));
        // defer-max: rescale only when wave-wide growth exceeds THR=8 (exp2)
        if (__any(pmax > mrow[mq] + 8.0f)) {
          const float mn = fmaxf(mrow[mq], pmax);
          const float scl = exp2f(mrow[mq] - mn);
          mrow[mq] = mn;
          lrow[mq] *= scl;
          float s0 = __shfl(scl, g * 4 + 0);
          float s1 = __shfl(scl, g * 4 + 1);
          float s2 = __shfl(scl, g * 4 + 2);
          float s3 = __shfl(scl, g * 4 + 3);
#pragma unroll
          for (int nf = 0; nf < 4; nf++) {
            f32x4 t = oacc[mq][nf];
            t[0] *= s0; t[1] *= s1; t[2] *= s2; t[3] *= s3;
            oacc[mq][nf] = t;
          }
        }
        float rsum = 0.f;
#pragma unroll
        for (int kf = 0; kf < 4; kf++) {
          short4 pk;
#pragma unroll
          for (int rr = 0; rr < 4; rr++) {
            const float p = exp2f(st[kf][mq][rr] - mrow[mq]);
            rsum += p;
            ((short*)&pk)[rr] = f2bf(p);
          }
          const int slot4 = (kf * 4 + g) ^ pkey;
          *(short4*)&pl[w][cr][slot4 * 4] = pk;
        }
        rsum += __shfl_xor(rsum, 16);
        rsum += __shfl_xor(rsum, 32);
        lrow[mq] += rsum;
        // ---- PV: pa from swizzled bounce, bv from sV (unchanged layout) ----
        const bf16x8 pa0 = *(const bf16x8*)&pl[w][cr][((2 * g) ^ pkey) * 4];
        const bf16x8 pa1 = *(const bf16x8*)&pl[w][cr][((2 * g + 8) ^ pkey) * 4];
        __builtin_amdgcn_s_setprio(1);
#pragma unroll
        for (int nf = 0; nf < 4; nf++) {
          const bf16x8 bv0 = *(const bf16x8*)&sV[cur][(nf * 16 + cr) * 64 + sg0];
          const bf16x8 bv1 = *(const bf16x8*)&sV[cur][(nf * 16 + cr) * 64 + sg1];
          oacc[mq][nf] = __builtin_amdgcn_mfma_f32_16x16x32_bf16(pa0, bv0, oacc[mq][nf], 0, 0, 0);
          oacc[mq][nf] = __builtin_amdgcn_mfma_f32_16x16x32_bf16(pa1, bv1, oacc[mq][nf], 0, 0, 0);
        }
        __builtin_amdgcn_s_setprio(0);
      }
    }

    if (kt + 1 < nkt) {
      asm volatile("s_waitcnt vmcnt(0)" ::: "memory");
      __syncthreads();
      cur ^= 1;
    }
  }

  // ---- write O: gather per-row denominators from lane cr = row ----
#pragma unroll
  for (int m = 0; m < 2; m++) {
    float il[4];
#pragma unroll
    for (int rr = 0; rr < 4; rr++)
      il[rr] = 1.0f / __shfl(lrow[m], g * 4 + rr);
#pragma unroll
    for (int nf = 0; nf < 4; nf++)
#pragma unroll
      for (int rr = 0; rr < 4; rr++) {
        const int row = qr0 + m * 16 + g * 4 + rr;
        o[(size_t)(b * 2048 + row) * 1024 + h * 64 + nf * 16 + cr] =
            __float2bfloat16(oacc[m][nf][rr] * il[rr]);
      }
  }
#undef STAGE_TILE
}

// ---------------------------------------------------------------------------
// Launch
// ---------------------------------------------------------------------------
extern "C" void kernel_launch(void* const* d_in, const int* in_sizes, int n_in,
                              void* d_out, int out_size, void* d_ws, size_t ws_size,
                              hipStream_t stream) {
  const float* x   = (const float*)d_in[0];
  const float* Wq  = (const float*)d_in[1];
  const float* Wk  = (const float*)d_in[2];
  const float* Wv  = (const float*)d_in[3];
  const float* Wo  = (const float*)d_in[4];
  const float* bo  = (const float*)d_in[5];
  const float* W1  = (const float*)d_in[6];
  const float* b1  = (const float*)d_in[7];
  const float* W2  = (const float*)d_in[8];
  const float* b2  = (const float*)d_in[9];
  const float* g1  = (const float*)d_in[10];
  const float* be1 = (const float*)d_in[11];
  const float* g2  = (const float*)d_in[12];
  const float* be2 = (const float*)d_in[13];

  char* ws = (char*)d_ws;
  const size_t MB = 1024 * 1024;
  __hip_bfloat16* hA    = (__hip_bfloat16*)(ws + 0);          // 16MB (LN1 out)
  __hip_bfloat16* attnO = (__hip_bfloat16*)(ws + 0);          // 16MB (reuse)
  __hip_bfloat16* qkv   = (__hip_bfloat16*)(ws + 16 * MB);    // 48MB
  float*          x2    = (float*)(ws + 16 * MB);             // 32MB (reuse qkv)
  __hip_bfloat16* h2    = (__hip_bfloat16*)(ws + 48 * MB);    // 16MB (reuse qkv tail)
  __hip_bfloat16* vtg   = (__hip_bfloat16*)(ws + 64 * MB);    // 16MB (dead after attn)
  __hip_bfloat16* act   = (__hip_bfloat16*)(ws + 64 * MB);    // 64MB (FFN1 out)
  __hip_bfloat16* WqkvT = (__hip_bfloat16*)(ws + 128 * MB);   // 6MB  [3072,1024]
  __hip_bfloat16* WoT   = (__hip_bfloat16*)(ws + 134 * MB);   // 2MB  [1024,1024]
  __hip_bfloat16* W1T   = (__hip_bfloat16*)(ws + 136 * MB);   // 8MB  [4096,1024]
  __hip_bfloat16* W2T   = (__hip_bfloat16*)(ws + 144 * MB);   // 8MB  [1024,4096]

  const dim3 tb(32, 8);
  tcvt_kernel<<<dim3(32, 32), tb, 0, stream>>>(Wq, WqkvT, 1024, 1024);
  tcvt_kernel<<<dim3(32, 32), tb, 0, stream>>>(Wk, WqkvT + 1024 * 1024, 1024, 1024);
  tcvt_kernel<<<dim3(32, 32), tb, 0, stream>>>(Wv, WqkvT + 2 * 1024 * 1024, 1024, 1024);
  tcvt_kernel<<<dim3(32, 32), tb, 0, stream>>>(Wo, WoT, 1024, 1024);
  tcvt_kernel<<<dim3(128, 32), tb, 0, stream>>>(W1, W1T, 1024, 4096);
  tcvt_kernel<<<dim3(32, 128), tb, 0, stream>>>(W2, W2T, 4096, 1024);

  ln_kernel<<<8192, 256, 0, stream>>>(x, g1, be1, hA);
  // QKV: 64x12 = 768 blocks (3.0 rounds), NPH=2
  gemm8<128, 256, 0><<<dim3(64, 12), 512, 0, stream>>>(
      hA, WqkvT, qkv, nullptr, nullptr, 3072, 1024);
  vtr_kernel<<<dim3(64, 2, 64), tb, 0, stream>>>(qkv, vtg);
  attn_kernel<<<1024, 256, 0, stream>>>(qkv, vtg, attnO);
  // O-proj: 64x4 = 256 blocks (1.0 round), NPH=2
  gemm8<128, 256, 1><<<dim3(64, 4), 512, 0, stream>>>(
      attnO, WoT, x2, bo, x, 1024, 1024);
  ln_kernel<<<8192, 256, 0, stream>>>(x2, g2, be2, h2);
  // FFN1: 32x16 = 512 blocks (2.0 rounds), NPH=4 (m201-verified shape)
  gemm8<256, 256, 2><<<dim3(32, 16), 512, 0, stream>>>(
      h2, W1T, act, b1, nullptr, 4096, 1024);
  // FFN2: 64x4 = 256 blocks (1.0 round), K=4096, NPH=2
  gemm8<128, 256, 1><<<dim3(64, 4), 512, 0, stream>>>(
      act, W2T, (float*)d_out, b2, x2, 1024, 4096);
  (void)in_sizes; (void)n_in; (void)out_size; (void)ws_size;
}